// Round 7
// baseline (462.937 us; speedup 1.0000x reference)
//
#include <hip/hip_runtime.h>
#include <hip/hip_bf16.h>
#include <math.h>

#define BB 2
#define SS 2048
#define NN 2049
#define MM (BB*NN)      // 4098 rows
#define DD 256
#define HR 128          // HEADS*RANK
#define NHEAD 4
#define WINW 64
#define DFF 512
#define EPSF 1e-6f
#define TB16 129        // ceil(NN/16) attn tiles per batch

typedef __attribute__((ext_vector_type(8))) short bf16x8;
typedef __attribute__((ext_vector_type(4))) float f32x4;

// ---------- helpers ----------
__device__ __forceinline__ float wave_sum(float v) {
    v += __shfl_down(v, 32, 64); v += __shfl_down(v, 16, 64);
    v += __shfl_down(v, 8, 64);  v += __shfl_down(v, 4, 64);
    v += __shfl_down(v, 2, 64);  v += __shfl_down(v, 1, 64);
    return v;
}
__device__ __forceinline__ float wave_max(float v) {
    v = fmaxf(v, __shfl_down(v, 32, 64)); v = fmaxf(v, __shfl_down(v, 16, 64));
    v = fmaxf(v, __shfl_down(v, 8, 64));  v = fmaxf(v, __shfl_down(v, 4, 64));
    v = fmaxf(v, __shfl_down(v, 2, 64));  v = fmaxf(v, __shfl_down(v, 1, 64));
    return v;
}
__device__ __forceinline__ float block_sum(float v, float* red) {
    v = wave_sum(v);
    __syncthreads();
    if ((threadIdx.x & 63) == 0) red[threadIdx.x >> 6] = v;
    __syncthreads();
    return red[0] + red[1] + red[2] + red[3];
}
__device__ __forceinline__ float sgnf(float x) {
    return (x > 0.f) ? 1.f : ((x < 0.f) ? -1.f : 0.f);
}
__device__ __forceinline__ ushort f2b(float x) {
    __hip_bfloat16 h = __float2bfloat16(x);
    return *(ushort*)&h;
}
__device__ __forceinline__ float b2f(ushort u) {
    unsigned int v = ((unsigned int)u) << 16;
    return *(float*)&v;
}
__device__ __forceinline__ void split3(float x, ushort& h, ushort& m, ushort& l) {
    h = f2b(x);
    float r1 = x - b2f(h);
    m = f2b(r1);
    l = f2b(r1 - b2f(m));
}
// MFMA-B fragment index map: element e of a packed (K,N) tensor
__device__ __forceinline__ void pack_map(int e, int N, int& k, int& n) {
    int j = e & 7;
    int l = (e >> 3) & 63;
    int c = e >> 9;
    int ntiles = N >> 4;
    int kt = c / ntiles, nt = c - kt * ntiles;
    k = kt * 32 + ((l >> 4) << 3) + j;
    n = nt * 16 + (l & 15);
}

// ---------- single fused weight-pack kernel (W1,W2 2-plane; U,V 3-plane) ----------
__global__ void packall_kernel(const float* __restrict__ W1, const float* __restrict__ W2,
                               const float* __restrict__ U,  const float* __restrict__ V,
                               ushort* __restrict__ W1ph, ushort* __restrict__ W1pl,
                               ushort* __restrict__ W2ph, ushort* __restrict__ W2pl,
                               ushort* __restrict__ U0, ushort* __restrict__ U1,
                               ushort* __restrict__ U2,
                               ushort* __restrict__ V0, ushort* __restrict__ V1,
                               ushort* __restrict__ V2) {
    int idx = blockIdx.x * 256 + threadIdx.x;   // < 3*327680
    int l = idx / 327680;
    int r = idx - l * 327680;
    if (l >= 3) return;
    int k, n;
    if (r < 131072) {                    // W1: (256,512)
        int e = r;
        pack_map(e, 512, k, n);
        float s = W1[(size_t)l * 131072 + (size_t)k * 512 + n];
        ushort h = f2b(s);
        W1ph[(size_t)l * 131072 + e] = h;
        W1pl[(size_t)l * 131072 + e] = f2b(s - b2f(h));
    } else if (r < 262144) {             // W2: (512,256)
        int e = r - 131072;
        pack_map(e, 256, k, n);
        float s = W2[(size_t)l * 131072 + (size_t)k * 256 + n];
        ushort h = f2b(s);
        W2ph[(size_t)l * 131072 + e] = h;
        W2pl[(size_t)l * 131072 + e] = f2b(s - b2f(h));
    } else if (r < 294912) {             // U: (256,128), 3 planes
        int e = r - 262144;
        pack_map(e, 128, k, n);
        ushort h, m, lo;
        split3(U[(size_t)l * 32768 + (size_t)k * 128 + n], h, m, lo);
        U0[(size_t)l * 32768 + e] = h;
        U1[(size_t)l * 32768 + e] = m;
        U2[(size_t)l * 32768 + e] = lo;
    } else {                             // V: (256,128), 3 planes
        int e = r - 294912;
        pack_map(e, 128, k, n);
        ushort h, m, lo;
        split3(V[(size_t)l * 32768 + (size_t)k * 128 + n], h, m, lo);
        V0[(size_t)l * 32768 + e] = h;
        V1[(size_t)l * 32768 + e] = m;
        V2[(size_t)l * 32768 + e] = lo;
    }
}

// ---------- embed ----------
__global__ void embed_kernel(const int* __restrict__ ids,
                             const float* __restrict__ emb,
                             const float* __restrict__ pos,
                             const float* __restrict__ anchor_val,
                             const float* __restrict__ anchor_state,
                             const float* __restrict__ Ws,
                             const float* __restrict__ bs,
                             float* __restrict__ val,
                             ushort* __restrict__ v0, ushort* __restrict__ v1,
                             ushort* __restrict__ v2,
                             float* __restrict__ state) {
    __shared__ float red[4];
    int row = blockIdx.x;
    int t = threadIdx.x;
    int b = row / NN, n = row % NN;
    float e;
    if (n == 0) {
        e = anchor_val[t];
    } else {
        int id = ids[b * SS + (n - 1)];
        e = emb[(size_t)id * DD + t] + pos[(size_t)(n - 1) * DD + t];
    }
    float ss = block_sum(e * e, red);
    float ts = block_sum(e * Ws[t], red);
    float rn = 1.f / fmaxf(sqrtf(ss), EPSF);
    float o = e * rn;
    size_t oi = (size_t)row * DD + t;
    val[oi] = o;
    ushort h, m, lo;
    split3(o, h, m, lo);
    v0[oi] = h; v1[oi] = m; v2[oi] = lo;
    if (t == 0) state[row] = (n == 0) ? anchor_state[0] : (ts + bs[0]);
}

// ---------- q/k projection: 6-term bf16 MFMA, register double-buffered ----------
__global__ __launch_bounds__(256, 1)
void proj_kernel(const ushort* __restrict__ X0, const ushort* __restrict__ X1,
                 const ushort* __restrict__ X2,
                 const ushort* __restrict__ U0, const ushort* __restrict__ U1,
                 const ushort* __restrict__ U2,
                 const ushort* __restrict__ V0, const ushort* __restrict__ V1,
                 const ushort* __restrict__ V2,
                 ushort* __restrict__ q0, ushort* __restrict__ q1,
                 ushort* __restrict__ q2,
                 ushort* __restrict__ k0, ushort* __restrict__ k1,
                 ushort* __restrict__ k2) {
    int t = threadIdx.x;
    int w = t >> 6, l = t & 63;
    int lm = l & 15, quad = l >> 4;
    int m0 = blockIdx.x * 16;
    int arow = m0 + lm; if (arow > MM - 1) arow = MM - 1;   // clamp: garbage rows unused
    const ushort* a0p = X0 + (size_t)arow * DD + quad * 8;
    const ushort* a1p = X1 + (size_t)arow * DD + quad * 8;
    const ushort* a2p = X2 + (size_t)arow * DD + quad * 8;
    bool isQ = (w < 2);
    const ushort* B0 = isQ ? U0 : V0;
    const ushort* B1 = isQ ? U1 : V1;
    const ushort* B2 = isQ ? U2 : V2;
    int ntb = (w & 1) * 4;
    f32x4 acc[4];
    #pragma unroll
    for (int j = 0; j < 4; j++) acc[j] = (f32x4)(0.f);

    bf16x8 a0, a1, a2, pb0[4], pb1[4], pb2[4];
    {
        a0 = *(const bf16x8*)(a0p);
        a1 = *(const bf16x8*)(a1p);
        a2 = *(const bf16x8*)(a2p);
        size_t cb = (((size_t)0 * 8 + ntb) * 64 + l) * 8;
        #pragma unroll
        for (int j = 0; j < 4; j++) {
            size_t o = cb + (size_t)j * 64 * 8;
            pb0[j] = *(const bf16x8*)(B0 + o);
            pb1[j] = *(const bf16x8*)(B1 + o);
            pb2[j] = *(const bf16x8*)(B2 + o);
        }
    }
    #pragma unroll
    for (int kt = 0; kt < 8; kt++) {
        bf16x8 na0, na1, na2, nb0[4], nb1[4], nb2[4];
        if (kt < 7) {
            na0 = *(const bf16x8*)(a0p + (kt + 1) * 32);
            na1 = *(const bf16x8*)(a1p + (kt + 1) * 32);
            na2 = *(const bf16x8*)(a2p + (kt + 1) * 32);
            size_t cb = (((size_t)(kt + 1) * 8 + ntb) * 64 + l) * 8;
            #pragma unroll
            for (int j = 0; j < 4; j++) {
                size_t o = cb + (size_t)j * 64 * 8;
                nb0[j] = *(const bf16x8*)(B0 + o);
                nb1[j] = *(const bf16x8*)(B1 + o);
                nb2[j] = *(const bf16x8*)(B2 + o);
            }
        }
        #pragma unroll
        for (int j = 0; j < 4; j++) {
            acc[j] = __builtin_amdgcn_mfma_f32_16x16x32_bf16(a0, pb0[j], acc[j], 0, 0, 0);
            acc[j] = __builtin_amdgcn_mfma_f32_16x16x32_bf16(a0, pb1[j], acc[j], 0, 0, 0);
            acc[j] = __builtin_amdgcn_mfma_f32_16x16x32_bf16(a1, pb0[j], acc[j], 0, 0, 0);
            acc[j] = __builtin_amdgcn_mfma_f32_16x16x32_bf16(a1, pb1[j], acc[j], 0, 0, 0);
            acc[j] = __builtin_amdgcn_mfma_f32_16x16x32_bf16(a0, pb2[j], acc[j], 0, 0, 0);
            acc[j] = __builtin_amdgcn_mfma_f32_16x16x32_bf16(a2, pb0[j], acc[j], 0, 0, 0);
        }
        if (kt < 7) {
            a0 = na0; a1 = na1; a2 = na2;
            #pragma unroll
            for (int j = 0; j < 4; j++) { pb0[j] = nb0[j]; pb1[j] = nb1[j]; pb2[j] = nb2[j]; }
        }
    }
    ushort* o0 = isQ ? q0 : k0;
    ushort* o1 = isQ ? q1 : k1;
    ushort* o2 = isQ ? q2 : k2;
    #pragma unroll
    for (int j = 0; j < 4; j++) {
        int o = (ntb + j) * 16 + lm;
        #pragma unroll
        for (int r = 0; r < 4; r++) {
            int row = m0 + quad * 4 + r;
            if (row < MM) {
                ushort h, m, lo;
                split3(acc[j][r], h, m, lo);
                size_t oi = (size_t)row * HR + o;
                o0[oi] = h; o1[oi] = m; o2[oi] = lo;
            }
        }
    }
}

// ---------- attention: 6-term MFMA scores + fp32 softmax + VALU dval ----------
__global__ __launch_bounds__(256, 1)
void attn_kernel(const float* __restrict__ val_in,
                 const float* __restrict__ state_in,
                 const ushort* __restrict__ q0, const ushort* __restrict__ q1,
                 const ushort* __restrict__ q2,
                 const ushort* __restrict__ k0, const ushort* __restrict__ k1,
                 const ushort* __restrict__ k2,
                 float* __restrict__ val_out,
                 ushort* __restrict__ vbH, ushort* __restrict__ vbM,
                 float* __restrict__ dstate_out) {
    __shared__ float sc4[NHEAD][16][148];
    __shared__ __align__(16) float wgt2[144][20];
    __shared__ float redS[16][4];
    __shared__ float redM[16][4];

    int b = blockIdx.x / TB16;
    int n0 = (blockIdx.x % TB16) * 16;
    int t = threadIdx.x;
    int w = t >> 6, l = t & 63;
    int lm = l & 15, quad = l >> 4;

    // ---- Phase A: scores per head (wave w = head w), double-buffered K loads
    {
        int qrow = n0 + lm; if (qrow > NN - 1) qrow = NN - 1;
        size_t qa = ((size_t)(b * NN + qrow)) * HR + w * 32 + quad * 8;
        bf16x8 a0 = *(const bf16x8*)(q0 + qa);
        bf16x8 a1 = *(const bf16x8*)(q1 + qa);
        bf16x8 a2 = *(const bf16x8*)(q2 + qa);
        bf16x8 c0, c1, c2;
        {
            int j = n0 - 64 + lm;
            j = (j < 0) ? 0 : ((j > NN - 1) ? NN - 1 : j);
            size_t ka = ((size_t)(b * NN + j)) * HR + w * 32 + quad * 8;
            c0 = *(const bf16x8*)(k0 + ka);
            c1 = *(const bf16x8*)(k1 + ka);
            c2 = *(const bf16x8*)(k2 + ka);
        }
        #pragma unroll
        for (int jt = 0; jt < 9; jt++) {
            bf16x8 d0, d1, d2;
            if (jt < 8) {
                int j = n0 - 64 + (jt + 1) * 16 + lm;
                j = (j < 0) ? 0 : ((j > NN - 1) ? NN - 1 : j);
                size_t ka = ((size_t)(b * NN + j)) * HR + w * 32 + quad * 8;
                d0 = *(const bf16x8*)(k0 + ka);
                d1 = *(const bf16x8*)(k1 + ka);
                d2 = *(const bf16x8*)(k2 + ka);
            }
            f32x4 acc = (f32x4)(0.f);
            acc = __builtin_amdgcn_mfma_f32_16x16x32_bf16(a0, c0, acc, 0, 0, 0);
            acc = __builtin_amdgcn_mfma_f32_16x16x32_bf16(a0, c1, acc, 0, 0, 0);
            acc = __builtin_amdgcn_mfma_f32_16x16x32_bf16(a1, c0, acc, 0, 0, 0);
            acc = __builtin_amdgcn_mfma_f32_16x16x32_bf16(a1, c1, acc, 0, 0, 0);
            acc = __builtin_amdgcn_mfma_f32_16x16x32_bf16(a0, c2, acc, 0, 0, 0);
            acc = __builtin_amdgcn_mfma_f32_16x16x32_bf16(a2, c0, acc, 0, 0, 0);
            #pragma unroll
            for (int r = 0; r < 4; r++)
                sc4[w][quad * 4 + r][jt * 16 + lm] = acc[r];
            if (jt < 8) { c0 = d0; c1 = d1; c2 = d2; }
        }
    }
    __syncthreads();

    // ---- Phase B: signed softmax per token (16 threads per token)
    {
        int m = t >> 4, p = t & 15;
        int n = n0 + m;
        bool tokv = (n < NN);
        float sv[9]; bool vv[9];
        float mx = -INFINITY;
        #pragma unroll
        for (int i = 0; i < 9; i++) {
            int tap = p + 16 * i;
            int j = n0 - 64 + tap;
            float s0 = sc4[0][m][tap], s1 = sc4[1][m][tap];
            float s2 = sc4[2][m][tap], s3 = sc4[3][m][tap];
            float s = fmaxf(fmaxf(s0, s1), fmaxf(s2, s3)) * 0.17677669529663687f;
            bool v = tokv && (tap >= m) && (tap <= m + 128) && (j >= 0) && (j < NN);
            sv[i] = s; vv[i] = v;
            if (v) mx = fmaxf(mx, fabsf(s));
        }
        for (int off = 8; off > 0; off >>= 1) mx = fmaxf(mx, __shfl_xor(mx, off, 64));
        float ee[9];
        float sum = 0.f;
        #pragma unroll
        for (int i = 0; i < 9; i++) {
            ee[i] = vv[i] ? expf(fabsf(sv[i]) - mx) : 0.f;
            sum += ee[i];
        }
        for (int off = 8; off > 0; off >>= 1) sum += __shfl_xor(sum, off, 64);
        float inv = (sum > 0.f) ? 1.f / sum : 0.f;
        float ds = 0.f;
        #pragma unroll
        for (int i = 0; i < 9; i++) {
            int tap = p + 16 * i;
            float wg = vv[i] ? sgnf(sv[i]) * ee[i] * inv : 0.f;
            wgt2[tap][m] = wg;
            if (vv[i]) ds += wg * state_in[b * NN + (n0 - 64 + tap)];
        }
        for (int off = 8; off > 0; off >>= 1) ds += __shfl_xor(ds, off, 64);
        if (p == 0 && tokv) dstate_out[b * NN + n] = ds;
    }
    __syncthreads();

    // ---- Phase C: dval = wgt @ V, 1-deep prefetch of val rows
    {
        int d = (t >> 2) * 4;
        int tg = t & 3;
        int jlo = (n0 >= 64) ? 0 : (64 - n0);
        int jhi = NN - 1 - n0 + 64; if (jhi > 143) jhi = 143;
        const float* vbase = val_in + ((size_t)(b * NN + n0 - 64)) * DD + d;
        f32x4 acc[4];
        #pragma unroll
        for (int ti = 0; ti < 4; ti++) acc[ti] = (f32x4)(0.f);
        f32x4 vcur = *(const f32x4*)(vbase + (size_t)jlo * DD);
        for (int jj = jlo; jj <= jhi; jj++) {
            f32x4 vnext;
            if (jj < jhi) vnext = *(const f32x4*)(vbase + (size_t)(jj + 1) * DD);
            f32x4 wv = *(const f32x4*)&wgt2[jj][tg * 4];
            #pragma unroll
            for (int ti = 0; ti < 4; ti++) {
                float ws = wv[ti];
                acc[ti][0] += vcur[0] * ws; acc[ti][1] += vcur[1] * ws;
                acc[ti][2] += vcur[2] * ws; acc[ti][3] += vcur[3] * ws;
            }
            vcur = vnext;
        }
        f32x4 u[4];
        #pragma unroll
        for (int ti = 0; ti < 4; ti++) {
            int n = n0 + tg * 4 + ti;
            f32x4 vold = (f32x4)(0.f);
            if (n < NN) vold = *(const f32x4*)(val_in + ((size_t)(b * NN + n)) * DD + d);
            u[ti] = vold + acc[ti];
            float s = u[ti][0]*u[ti][0] + u[ti][1]*u[ti][1] + u[ti][2]*u[ti][2] + u[ti][3]*u[ti][3];
            float mb = fmaxf(fmaxf(fabsf(acc[ti][0]), fabsf(acc[ti][1])),
                             fmaxf(fabsf(acc[ti][2]), fabsf(acc[ti][3])));
            for (int off = 4; off <= 32; off <<= 1) {
                s += __shfl_xor(s, off, 64);
                mb = fmaxf(mb, __shfl_xor(mb, off, 64));
            }
            if ((l >> 2) == 0) { redS[tg * 4 + ti][w] = s; redM[tg * 4 + ti][w] = mb; }
        }
        __syncthreads();
        #pragma unroll
        for (int ti = 0; ti < 4; ti++) {
            int tok = tg * 4 + ti;
            int n = n0 + tok;
            if (n < NN) {
                float ss = redS[tok][0] + redS[tok][1] + redS[tok][2] + redS[tok][3];
                float mab = fmaxf(fmaxf(redM[tok][0], redM[tok][1]),
                                  fmaxf(redM[tok][2], redM[tok][3]));
                float rn = 1.f / fmaxf(sqrtf(ss), EPSF);
                f32x4 o = u[ti];
                if (mab > 0.f) { o[0] *= rn; o[1] *= rn; o[2] *= rn; o[3] *= rn; }
                size_t oi = ((size_t)(b * NN + n)) * DD + d;
                *(f32x4*)(val_out + oi) = o;
                ushort4 hv, mv;
                {
                    ushort h0 = f2b(o[0]); hv.x = h0; mv.x = f2b(o[0] - b2f(h0));
                    ushort h1 = f2b(o[1]); hv.y = h1; mv.y = f2b(o[1] - b2f(h1));
                    ushort h2 = f2b(o[2]); hv.z = h2; mv.z = f2b(o[2] - b2f(h2));
                    ushort h3 = f2b(o[3]); hv.w = h3; mv.w = f2b(o[3] - b2f(h3));
                }
                *(ushort4*)(vbH + oi) = hv;
                *(ushort4*)(vbM + oi) = mv;
            }
        }
    }
}

// ---------- state update ----------
__global__ void state_kernel(const float* __restrict__ state_in,
                             const float* __restrict__ dstate,
                             float* __restrict__ state_out) {
    __shared__ float xs[NN];
    __shared__ float redA[16];
    __shared__ float redB[16];
    int b = blockIdx.x, t = threadIdx.x;
    float lmax = -INFINITY;
    for (int n = t; n < NN; n += 1024) {
        float x = state_in[b * NN + n] + dstate[b * NN + n];
        xs[n] = x;
        lmax = fmaxf(lmax, fabsf(x));
    }
    lmax = wave_max(lmax);
    if ((t & 63) == 0) redA[t >> 6] = lmax;
    __syncthreads();
    float m = redA[0];
    #pragma unroll
    for (int i = 1; i < 16; i++) m = fmaxf(m, redA[i]);
    float lsum = 0.f;
    for (int n = t; n < NN; n += 1024) lsum += expf(fabsf(xs[n]) - m);
    lsum = wave_sum(lsum);
    if ((t & 63) == 0) redB[t >> 6] = lsum;
    __syncthreads();
    float ssum = 0.f;
    #pragma unroll
    for (int i = 0; i < 16; i++) ssum += redB[i];
    float inv = 1.f / ssum;
    for (int n = t; n < NN; n += 1024) {
        float x = xs[n];
        state_out[b * NN + n] = sgnf(x) * expf(fabsf(x) - m) * inv;
    }
}

// ---------- FFN: bf16x3 MFMA, register double-buffered ----------
__global__ __launch_bounds__(256, 1)
void ffn_kernel(const ushort* __restrict__ XbH, const ushort* __restrict__ XbM,
                const float*  __restrict__ Xf,
                const ushort* __restrict__ W1h, const ushort* __restrict__ W1l,
                const float*  __restrict__ b1,
                const ushort* __restrict__ W2h, const ushort* __restrict__ W2l,
                const float*  __restrict__ b2,
                float* __restrict__ val_out,
                ushort* __restrict__ o0, ushort* __restrict__ o1,
                ushort* __restrict__ o2) {
    __shared__ ushort HtH[16 * 520];
    __shared__ ushort HtL[16 * 520];
    __shared__ float red[16][17];
    __shared__ float rrn[16];
    float* Yt = (float*)HtH;

    int t = threadIdx.x;
    int w = t >> 6, l = t & 63;
    int m0 = blockIdx.x * 16;
    int lm = l & 15;
    int lk = (l >> 4) << 3;
    int cm = (l >> 4) << 2;

    // ---- GEMM1: X(16x256)@W1(256x512), wave w -> n in [128w,128w+128)
    f32x4 acc[8];
    #pragma unroll
    for (int i = 0; i < 8; i++) acc[i] = (f32x4)(0.f);
    int arow = m0 + lm; if (arow > MM - 1) arow = MM - 1;   // clamp: extra rows unused
    const ushort* ah_base = XbH + (size_t)arow * DD + lk;
    const ushort* al_base = XbM + (size_t)arow * DD + lk;

    bf16x8 afh, afl, bh[8], bl[8];
    {
        afh = *(const bf16x8*)(ah_base);
        afl = *(const bf16x8*)(al_base);
        size_t cb = (((size_t)0 * 32 + w * 8) * 64 + l) * 8;
        #pragma unroll
        for (int n = 0; n < 8; n++) {
            bh[n] = *(const bf16x8*)(W1h + cb + (size_t)n * 512);
            bl[n] = *(const bf16x8*)(W1l + cb + (size_t)n * 512);
        }
    }
    #pragma unroll
    for (int kt = 0; kt < 8; kt++) {
        bf16x8 nafh, nafl, nbh[8], nbl[8];
        if (kt < 7) {
            nafh = *(const bf16x8*)(ah_base + (kt + 1) * 32);
            nafl = *(const bf16x8*)(al_base + (kt + 1) * 32);
            size_t cb = (((size_t)(kt + 1) * 32 + w * 8) * 64 + l) * 8;
            #pragma unroll
            for (int n = 0; n < 8; n++) {
                nbh[n] = *(const bf16x8*)(W1h + cb + (size_t)n * 512);
                nbl[n] = *(const bf16x8*)(W1l + cb + (size_t)n * 512);
            }
        }
        #pragma unroll
        for (int n = 0; n < 8; n++) {
            acc[n] = __builtin_amdgcn_mfma_f32_16x16x32_bf16(afh, bh[n], acc[n], 0, 0, 0);
            acc[n] = __builtin_amdgcn_mfma_f32_16x16x32_bf16(afl, bh[n], acc[n], 0, 0, 0);
            acc[n] = __builtin_amdgcn_mfma_f32_16x16x32_bf16(afh, bl[n], acc[n], 0, 0, 0);
        }
        if (kt < 7) {
            afh = nafh; afl = nafl;
            #pragma unroll
            for (int n = 0; n < 8; n++) { bh[n] = nbh[n]; bl[n] = nbl[n]; }
        }
    }
    #pragma unroll
    for (int n = 0; n < 8; n++) {
        int gn = w * 128 + n * 16 + lm;
        float bb = b1[gn];
        #pragma unroll
        for (int r = 0; r < 4; r++) {
            float x = acc[n][r] + bb;
            float g = 0.5f * x * (1.f + erff(x * 0.70710678118654752f));
            ushort gh = f2b(g);
            HtH[(cm + r) * 520 + gn] = gh;
            HtL[(cm + r) * 520 + gn] = f2b(g - b2f(gh));
        }
    }
    __syncthreads();

    // ---- GEMM2: H(16x512)@W2(512x256), wave w -> n in [64w,64w+64)
    f32x4 acc2[4];
    #pragma unroll
    for (int i = 0; i < 4; i++) acc2[i] = (f32x4)(0.f);
    bf16x8 b2h[4], b2l[4];
    {
        size_t cb = (((size_t)0 * 16 + w * 4) * 64 + l) * 8;
        #pragma unroll
        for (int n = 0; n < 4; n++) {
            b2h[n] = *(const bf16x8*)(W2h + cb + (size_t)n * 512);
            b2l[n] = *(const bf16x8*)(W2l + cb + (size_t)n * 512);
        }
    }
    #pragma unroll
    for (int kt = 0; kt < 16; kt++) {
        bf16x8 nb2h[4], nb2l[4];
        if (kt < 15) {
            size_t cb = (((size_t)(kt + 1) * 16 + w * 4) * 64 + l) * 8;
            #pragma unroll
            for (int n = 0; n < 4; n++) {
                nb2h[n] = *(const bf16x8*)(W2h + cb + (size_t)n * 512);
                nb2l[n] = *(const bf16x8*)(W2l + cb + (size_t)n * 512);
            }
        }
        bf16x8 afh2 = *(const bf16x8*)(HtH + lm * 520 + kt * 32 + lk);
        bf16x8 afl2 = *(const bf16x8*)(HtL + lm * 520 + kt * 32 + lk);
        #pragma unroll
        for (int n = 0; n < 4; n++) {
            acc2[n] = __builtin_amdgcn_mfma_f32_16x16x32_bf16(afh2, b2h[n], acc2[n], 0, 0, 0);
            acc2[n] = __builtin_amdgcn_mfma_f32_16x16x32_bf16(afl2, b2h[n], acc2[n], 0, 0, 0);
            acc2[n] = __builtin_amdgcn_mfma_f32_16x16x32_bf16(afh2, b2l[n], acc2[n], 0, 0, 0);
        }
        if (kt < 15) {
            #pragma unroll
            for (int n = 0; n < 4; n++) { b2h[n] = nb2h[n]; b2l[n] = nb2l[n]; }
        }
    }
    __syncthreads();   // done with Ht; reuse as Yt

    #pragma unroll
    for (int n = 0; n < 4; n++) {
        int gn = w * 64 + n * 16 + lm;
        float bb = b2[gn];
        #pragma unroll
        for (int r = 0; r < 4; r++) {
            int row = m0 + cm + r;
            float xv = (row < MM) ? Xf[(size_t)row * DD + gn] : 0.f;
            Yt[(cm + r) * 257 + gn] = xv + acc2[n][r] + bb;
        }
    }
    __syncthreads();
    {
        int m = t & 15, p = t >> 4;
        float s = 0.f;
        #pragma unroll
        for (int i = 0; i < 16; i++) { float y = Yt[m * 257 + p * 16 + i]; s += y * y; }
        red[m][p] = s;
    }
    __syncthreads();
    if (t < 16) {
        float s = 0.f;
        #pragma unroll
        for (int i = 0; i < 16; i++) s += red[t][i];
        rrn[t] = 1.f / fmaxf(sqrtf(s), EPSF);
    }
    __syncthreads();
    #pragma unroll
    for (int m = 0; m < 16; m++) {
        int row = m0 + m;
        if (row < MM) {
            float o = Yt[m * 257 + t] * rrn[m];
            size_t oi = (size_t)row * DD + t;
            val_out[oi] = o;
            ushort h, mm, lo;
            split3(o, h, mm, lo);
            o0[oi] = h; o1[oi] = mm; o2[oi] = lo;
        }
    }
}

extern "C" void kernel_launch(void* const* d_in, const int* in_sizes, int n_in,
                              void* d_out, int out_size, void* d_ws, size_t ws_size,
                              hipStream_t stream) {
    const int*   ids          = (const int*)d_in[0];
    const float* emb          = (const float*)d_in[1];
    const float* pos          = (const float*)d_in[2];
    const float* anchor_val   = (const float*)d_in[3];
    const float* anchor_state = (const float*)d_in[4];
    const float* Ws           = (const float*)d_in[5];
    const float* bs           = (const float*)d_in[6];
    const float* U            = (const float*)d_in[7];
    const float* V            = (const float*)d_in[8];
    const float* W1           = (const float*)d_in[9];
    const float* b1           = (const float*)d_in[10];
    const float* W2           = (const float*)d_in[11];
    const float* b2           = (const float*)d_in[12];
    float* out = (float*)d_out;

    // ---- workspace ----
    ushort* p = (ushort*)d_ws;
    ushort* vA0 = p; p += (size_t)MM * DD;
    ushort* vA1 = p; p += (size_t)MM * DD;
    ushort* vA2 = p; p += (size_t)MM * DD;
    ushort* vB0 = p; p += (size_t)MM * DD;
    ushort* vB1 = p; p += (size_t)MM * DD;
    ushort* q0b = p; p += (size_t)MM * HR;
    ushort* q1b = p; p += (size_t)MM * HR;
    ushort* q2b = p; p += (size_t)MM * HR;
    ushort* k0b = p; p += (size_t)MM * HR;
    ushort* k1b = p; p += (size_t)MM * HR;
    ushort* k2b = p; p += (size_t)MM * HR;
    ushort* W1ph = p; p += 3 * 131072;
    ushort* W1pl = p; p += 3 * 131072;
    ushort* W2ph = p; p += 3 * 131072;
    ushort* W2pl = p; p += 3 * 131072;
    ushort* U0p = p; p += 3 * 32768;
    ushort* U1p = p; p += 3 * 32768;
    ushort* U2p = p; p += 3 * 32768;
    ushort* V0p = p; p += 3 * 32768;
    ushort* V1p = p; p += 3 * 32768;
    ushort* V2p = p; p += 3 * 32768;
    float* f = (float*)p;
    float* valA = f; f += (size_t)MM * DD;
    float* valB = f; f += (size_t)MM * DD;
    float* st0  = f; f += MM;
    float* st1  = f; f += MM;
    float* dst  = f; f += MM;

    packall_kernel<<<3840, 256, 0, stream>>>(W1, W2, U, V,
                                             W1ph, W1pl, W2ph, W2pl,
                                             U0p, U1p, U2p, V0p, V1p, V2p);

    embed_kernel<<<MM, 256, 0, stream>>>(ids, emb, pos, anchor_val, anchor_state,
                                         Ws, bs, valA, vA0, vA1, vA2, st0);
    float* s_in = st0;
    float* s_out = st1;
    for (int l = 0; l < 3; l++) {
        proj_kernel<<<(MM + 15) / 16, 256, 0, stream>>>(
            vA0, vA1, vA2,
            U0p + (size_t)l * 32768, U1p + (size_t)l * 32768, U2p + (size_t)l * 32768,
            V0p + (size_t)l * 32768, V1p + (size_t)l * 32768, V2p + (size_t)l * 32768,
            q0b, q1b, q2b, k0b, k1b, k2b);
        attn_kernel<<<BB * TB16, 256, 0, stream>>>(valA, s_in,
                                                   q0b, q1b, q2b, k0b, k1b, k2b,
                                                   valB, vB0, vB1, dst);
        state_kernel<<<BB, 1024, 0, stream>>>(s_in, dst, (l == 2) ? out : s_out);
        ffn_kernel<<<(MM + 15) / 16, 256, 0, stream>>>(
            vB0, vB1, valB,
            W1ph + (size_t)l * 131072, W1pl + (size_t)l * 131072, b1 + (size_t)l * DFF,
            W2ph + (size_t)l * 131072, W2pl + (size_t)l * 131072, b2 + (size_t)l * DD,
            (l == 2) ? (out + MM) : valA, vA0, vA1, vA2);
        float* tmp = s_in; s_in = s_out; s_out = tmp;
    }
}

// Round 8
// 416.725 us; speedup vs baseline: 1.1109x; 1.1109x over previous
//
#include <hip/hip_runtime.h>
#include <hip/hip_bf16.h>
#include <math.h>

#define BB 2
#define SS 2048
#define NN 2049
#define MM (BB*NN)      // 4098 rows
#define DD 256
#define HR 128          // HEADS*RANK
#define NHEAD 4
#define WINW 64
#define DFF 512
#define EPSF 1e-6f
#define TB8 257         // ceil(NN/8) attn tiles per batch

typedef __attribute__((ext_vector_type(8))) short bf16x8;
typedef __attribute__((ext_vector_type(4))) float f32x4;

// ---------- helpers ----------
__device__ __forceinline__ float wave_sum(float v) {
    v += __shfl_down(v, 32, 64); v += __shfl_down(v, 16, 64);
    v += __shfl_down(v, 8, 64);  v += __shfl_down(v, 4, 64);
    v += __shfl_down(v, 2, 64);  v += __shfl_down(v, 1, 64);
    return v;
}
__device__ __forceinline__ float wave_max(float v) {
    v = fmaxf(v, __shfl_down(v, 32, 64)); v = fmaxf(v, __shfl_down(v, 16, 64));
    v = fmaxf(v, __shfl_down(v, 8, 64));  v = fmaxf(v, __shfl_down(v, 4, 64));
    v = fmaxf(v, __shfl_down(v, 2, 64));  v = fmaxf(v, __shfl_down(v, 1, 64));
    return v;
}
__device__ __forceinline__ float block_sum(float v, float* red) {
    v = wave_sum(v);
    __syncthreads();
    if ((threadIdx.x & 63) == 0) red[threadIdx.x >> 6] = v;
    __syncthreads();
    return red[0] + red[1] + red[2] + red[3];
}
__device__ __forceinline__ float sgnf(float x) {
    return (x > 0.f) ? 1.f : ((x < 0.f) ? -1.f : 0.f);
}
__device__ __forceinline__ ushort f2b(float x) {
    __hip_bfloat16 h = __float2bfloat16(x);
    return *(ushort*)&h;
}
__device__ __forceinline__ float b2f(ushort u) {
    unsigned int v = ((unsigned int)u) << 16;
    return *(float*)&v;
}
__device__ __forceinline__ void split3(float x, ushort& h, ushort& m, ushort& l) {
    h = f2b(x);
    float r1 = x - b2f(h);
    m = f2b(r1);
    l = f2b(r1 - b2f(m));
}
__device__ __forceinline__ void pack_map(int e, int N, int& k, int& n) {
    int j = e & 7;
    int l = (e >> 3) & 63;
    int c = e >> 9;
    int ntiles = N >> 4;
    int kt = c / ntiles, nt = c - kt * ntiles;
    k = kt * 32 + ((l >> 4) << 3) + j;
    n = nt * 16 + (l & 15);
}

// ---------- fused weight pack ----------
__global__ void packall_kernel(const float* __restrict__ W1, const float* __restrict__ W2,
                               const float* __restrict__ U,  const float* __restrict__ V,
                               ushort* __restrict__ W1ph, ushort* __restrict__ W1pl,
                               ushort* __restrict__ W2ph, ushort* __restrict__ W2pl,
                               ushort* __restrict__ U0, ushort* __restrict__ U1,
                               ushort* __restrict__ U2,
                               ushort* __restrict__ V0, ushort* __restrict__ V1,
                               ushort* __restrict__ V2) {
    int idx = blockIdx.x * 256 + threadIdx.x;
    int l = idx / 327680;
    int r = idx - l * 327680;
    if (l >= 3) return;
    int k, n;
    if (r < 131072) {
        int e = r;
        pack_map(e, 512, k, n);
        float s = W1[(size_t)l * 131072 + (size_t)k * 512 + n];
        ushort h = f2b(s);
        W1ph[(size_t)l * 131072 + e] = h;
        W1pl[(size_t)l * 131072 + e] = f2b(s - b2f(h));
    } else if (r < 262144) {
        int e = r - 131072;
        pack_map(e, 256, k, n);
        float s = W2[(size_t)l * 131072 + (size_t)k * 256 + n];
        ushort h = f2b(s);
        W2ph[(size_t)l * 131072 + e] = h;
        W2pl[(size_t)l * 131072 + e] = f2b(s - b2f(h));
    } else if (r < 294912) {
        int e = r - 262144;
        pack_map(e, 128, k, n);
        ushort h, m, lo;
        split3(U[(size_t)l * 32768 + (size_t)k * 128 + n], h, m, lo);
        U0[(size_t)l * 32768 + e] = h;
        U1[(size_t)l * 32768 + e] = m;
        U2[(size_t)l * 32768 + e] = lo;
    } else {
        int e = r - 294912;
        pack_map(e, 128, k, n);
        ushort h, m, lo;
        split3(V[(size_t)l * 32768 + (size_t)k * 128 + n], h, m, lo);
        V0[(size_t)l * 32768 + e] = h;
        V1[(size_t)l * 32768 + e] = m;
        V2[(size_t)l * 32768 + e] = lo;
    }
}

// ---------- embed ----------
__global__ void embed_kernel(const int* __restrict__ ids,
                             const float* __restrict__ emb,
                             const float* __restrict__ pos,
                             const float* __restrict__ anchor_val,
                             const float* __restrict__ anchor_state,
                             const float* __restrict__ Ws,
                             const float* __restrict__ bs,
                             float* __restrict__ val,
                             ushort* __restrict__ v0, ushort* __restrict__ v1,
                             ushort* __restrict__ v2,
                             float* __restrict__ state) {
    __shared__ float red[4];
    int row = blockIdx.x;
    int t = threadIdx.x;
    int b = row / NN, n = row % NN;
    float e;
    if (n == 0) {
        e = anchor_val[t];
    } else {
        int id = ids[b * SS + (n - 1)];
        e = emb[(size_t)id * DD + t] + pos[(size_t)(n - 1) * DD + t];
    }
    float ss = block_sum(e * e, red);
    float ts = block_sum(e * Ws[t], red);
    float rn = 1.f / fmaxf(sqrtf(ss), EPSF);
    float o = e * rn;
    size_t oi = (size_t)row * DD + t;
    val[oi] = o;
    ushort h, m, lo;
    split3(o, h, m, lo);
    v0[oi] = h; v1[oi] = m; v2[oi] = lo;
    if (t == 0) state[row] = (n == 0) ? anchor_state[0] : (ts + bs[0]);
}

// ---------- q/k projection: 6-term MFMA, 8-token blocks, A upfront ----------
__global__ __launch_bounds__(256, 2)
void proj_kernel(const ushort* __restrict__ X0, const ushort* __restrict__ X1,
                 const ushort* __restrict__ X2,
                 const ushort* __restrict__ U0, const ushort* __restrict__ U1,
                 const ushort* __restrict__ U2,
                 const ushort* __restrict__ V0, const ushort* __restrict__ V1,
                 const ushort* __restrict__ V2,
                 ushort* __restrict__ q0, ushort* __restrict__ q1,
                 ushort* __restrict__ q2,
                 ushort* __restrict__ k0, ushort* __restrict__ k1,
                 ushort* __restrict__ k2) {
    int t = threadIdx.x;
    int w = t >> 6, l = t & 63;
    int lm = l & 15, quad = l >> 4;
    int m0 = blockIdx.x * 8;
    int arow = m0 + lm; if (arow > MM - 1) arow = MM - 1;   // rows >=8 unused in C
    const ushort* a0p = X0 + (size_t)arow * DD + quad * 8;
    const ushort* a1p = X1 + (size_t)arow * DD + quad * 8;
    const ushort* a2p = X2 + (size_t)arow * DD + quad * 8;
    bool isQ = (w < 2);
    const ushort* B0 = isQ ? U0 : V0;
    const ushort* B1 = isQ ? U1 : V1;
    const ushort* B2 = isQ ? U2 : V2;
    int ntb = (w & 1) * 4;

    // A fragments upfront (24 independent loads in flight)
    bf16x8 af0[8], af1[8], af2[8];
    #pragma unroll
    for (int kt = 0; kt < 8; kt++) {
        af0[kt] = *(const bf16x8*)(a0p + kt * 32);
        af1[kt] = *(const bf16x8*)(a1p + kt * 32);
        af2[kt] = *(const bf16x8*)(a2p + kt * 32);
    }
    f32x4 acc[4];
    #pragma unroll
    for (int j = 0; j < 4; j++) acc[j] = (f32x4)(0.f);
    #pragma unroll
    for (int kt = 0; kt < 8; kt++) {
        size_t cb = (((size_t)kt * 8 + ntb) * 64 + l) * 8;
        bf16x8 b0[4], b1[4], b2[4];
        #pragma unroll
        for (int j = 0; j < 4; j++) {
            size_t o = cb + (size_t)j * 64 * 8;
            b0[j] = *(const bf16x8*)(B0 + o);
            b1[j] = *(const bf16x8*)(B1 + o);
            b2[j] = *(const bf16x8*)(B2 + o);
        }
        #pragma unroll
        for (int j = 0; j < 4; j++) {
            acc[j] = __builtin_amdgcn_mfma_f32_16x16x32_bf16(af0[kt], b0[j], acc[j], 0, 0, 0);
            acc[j] = __builtin_amdgcn_mfma_f32_16x16x32_bf16(af0[kt], b1[j], acc[j], 0, 0, 0);
            acc[j] = __builtin_amdgcn_mfma_f32_16x16x32_bf16(af1[kt], b0[j], acc[j], 0, 0, 0);
            acc[j] = __builtin_amdgcn_mfma_f32_16x16x32_bf16(af1[kt], b1[j], acc[j], 0, 0, 0);
            acc[j] = __builtin_amdgcn_mfma_f32_16x16x32_bf16(af0[kt], b2[j], acc[j], 0, 0, 0);
            acc[j] = __builtin_amdgcn_mfma_f32_16x16x32_bf16(af2[kt], b0[j], acc[j], 0, 0, 0);
        }
    }
    ushort* o0 = isQ ? q0 : k0;
    ushort* o1 = isQ ? q1 : k1;
    ushort* o2 = isQ ? q2 : k2;
    if (quad < 2) {   // C rows 0..7 only
        #pragma unroll
        for (int j = 0; j < 4; j++) {
            int o = (ntb + j) * 16 + lm;
            #pragma unroll
            for (int r = 0; r < 4; r++) {
                int row = m0 + quad * 4 + r;
                if (row < MM) {
                    ushort h, m, lo;
                    split3(acc[j][r], h, m, lo);
                    size_t oi = (size_t)row * HR + o;
                    o0[oi] = h; o1[oi] = m; o2[oi] = lo;
                }
            }
        }
    }
}

// ---------- attention: 8-token tiles, upfront K loads, fp32 softmax, batched dval ----------
__global__ __launch_bounds__(256, 2)
void attn_kernel(const float* __restrict__ val_in,
                 const float* __restrict__ state_in,
                 const ushort* __restrict__ q0, const ushort* __restrict__ q1,
                 const ushort* __restrict__ q2,
                 const ushort* __restrict__ k0, const ushort* __restrict__ k1,
                 const ushort* __restrict__ k2,
                 float* __restrict__ val_out,
                 ushort* __restrict__ vbH, ushort* __restrict__ vbM,
                 float* __restrict__ dstate_out) {
    __shared__ float sc4[NHEAD][8][148];           // 18.9 KB
    __shared__ float wgt2[144][12];                // 6.9 KB
    __shared__ float redS[8][4];
    __shared__ float redM[8][4];

    int b = blockIdx.x / TB8;
    int n0 = (blockIdx.x % TB8) * 8;
    int t = threadIdx.x;
    int w = t >> 6, l = t & 63;
    int lm = l & 15, quad = l >> 4;

    // ---- Phase A: all 27 K-fragment loads upfront, then 54 MFMAs
    {
        int qrow = n0 + (lm & 7);                  // tokens 0..7 (dup rows 8..15, unused)
        if (qrow > NN - 1) qrow = NN - 1;
        size_t qa = ((size_t)(b * NN + qrow)) * HR + w * 32 + quad * 8;
        bf16x8 a0 = *(const bf16x8*)(q0 + qa);
        bf16x8 a1 = *(const bf16x8*)(q1 + qa);
        bf16x8 a2 = *(const bf16x8*)(q2 + qa);
        bf16x8 kf0[9], kf1[9], kf2[9];
        #pragma unroll
        for (int jt = 0; jt < 9; jt++) {
            int j = n0 - 64 + jt * 16 + lm;
            j = (j < 0) ? 0 : ((j > NN - 1) ? NN - 1 : j);
            size_t ka = ((size_t)(b * NN + j)) * HR + w * 32 + quad * 8;
            kf0[jt] = *(const bf16x8*)(k0 + ka);
            kf1[jt] = *(const bf16x8*)(k1 + ka);
            kf2[jt] = *(const bf16x8*)(k2 + ka);
        }
        #pragma unroll
        for (int jt = 0; jt < 9; jt++) {
            f32x4 acc = (f32x4)(0.f);
            acc = __builtin_amdgcn_mfma_f32_16x16x32_bf16(a0, kf0[jt], acc, 0, 0, 0);
            acc = __builtin_amdgcn_mfma_f32_16x16x32_bf16(a0, kf1[jt], acc, 0, 0, 0);
            acc = __builtin_amdgcn_mfma_f32_16x16x32_bf16(a1, kf0[jt], acc, 0, 0, 0);
            acc = __builtin_amdgcn_mfma_f32_16x16x32_bf16(a1, kf1[jt], acc, 0, 0, 0);
            acc = __builtin_amdgcn_mfma_f32_16x16x32_bf16(a0, kf2[jt], acc, 0, 0, 0);
            acc = __builtin_amdgcn_mfma_f32_16x16x32_bf16(a2, kf0[jt], acc, 0, 0, 0);
            if (quad < 2) {                        // C rows 0..7 = tokens
                #pragma unroll
                for (int r = 0; r < 4; r++)
                    sc4[w][quad * 4 + r][jt * 16 + lm] = acc[r];
            }
        }
    }
    __syncthreads();

    // ---- Phase B: signed softmax; 32 threads per token (8 tokens)
    {
        int m = t >> 5, p = t & 31;
        int n = n0 + m;
        bool tokv = (n < NN);
        float sv[5]; bool vv[5];
        float mx = -INFINITY;
        #pragma unroll
        for (int i = 0; i < 5; i++) {
            int tap = p + 32 * i;
            bool inb = (tap < 144);
            int tapc = inb ? tap : 0;
            int j = n0 - 64 + tapc;
            float s0 = sc4[0][m][tapc], s1 = sc4[1][m][tapc];
            float s2 = sc4[2][m][tapc], s3 = sc4[3][m][tapc];
            float s = fmaxf(fmaxf(s0, s1), fmaxf(s2, s3)) * 0.17677669529663687f;
            bool v = inb && tokv && (tap >= m) && (tap <= m + 128) && (j >= 0) && (j < NN);
            sv[i] = s; vv[i] = v;
            if (v) mx = fmaxf(mx, fabsf(s));
        }
        for (int off = 16; off > 0; off >>= 1) mx = fmaxf(mx, __shfl_xor(mx, off, 64));
        float ee[5];
        float sum = 0.f;
        #pragma unroll
        for (int i = 0; i < 5; i++) {
            ee[i] = vv[i] ? expf(fabsf(sv[i]) - mx) : 0.f;
            sum += ee[i];
        }
        for (int off = 16; off > 0; off >>= 1) sum += __shfl_xor(sum, off, 64);
        float inv = (sum > 0.f) ? 1.f / sum : 0.f;
        float ds = 0.f;
        #pragma unroll
        for (int i = 0; i < 5; i++) {
            int tap = p + 32 * i;
            if (tap < 144) {
                float wg = vv[i] ? sgnf(sv[i]) * ee[i] * inv : 0.f;
                wgt2[tap][m] = wg;
                if (vv[i]) ds += wg * state_in[b * NN + (n0 - 64 + tap)];
            }
        }
        for (int off = 16; off > 0; off >>= 1) ds += __shfl_xor(ds, off, 64);
        if (p == 0 && tokv) dstate_out[b * NN + n] = ds;
    }
    __syncthreads();

    // ---- Phase C: dval, thread = (d 4-wide) x (2 tokens), 4-deep batched loads
    {
        int d = (t >> 2) * 4;
        int tg = t & 3;
        int tok0 = tg * 2, tok1 = tg * 2 + 1;
        int jlo = (n0 >= 64) ? 0 : (64 - n0);
        int jhi = NN - 1 - n0 + 64; if (jhi > 135) jhi = 135;
        const float* vbase = val_in + ((size_t)(b * NN + n0 - 64)) * DD + d;
        f32x4 acc0 = (f32x4)(0.f), acc1 = (f32x4)(0.f);
        int jj = jlo;
        for (; jj + 3 <= jhi; jj += 4) {
            f32x4 v0 = *(const f32x4*)(vbase + (size_t)(jj + 0) * DD);
            f32x4 v1 = *(const f32x4*)(vbase + (size_t)(jj + 1) * DD);
            f32x4 v2 = *(const f32x4*)(vbase + (size_t)(jj + 2) * DD);
            f32x4 v3 = *(const f32x4*)(vbase + (size_t)(jj + 3) * DD);
            float wa0 = wgt2[jj + 0][tok0], wa1 = wgt2[jj + 0][tok1];
            float wb0 = wgt2[jj + 1][tok0], wb1 = wgt2[jj + 1][tok1];
            float wc0 = wgt2[jj + 2][tok0], wc1 = wgt2[jj + 2][tok1];
            float wd0 = wgt2[jj + 3][tok0], wd1 = wgt2[jj + 3][tok1];
            #pragma unroll
            for (int c = 0; c < 4; c++) {
                acc0[c] += v0[c] * wa0 + v1[c] * wb0 + v2[c] * wc0 + v3[c] * wd0;
                acc1[c] += v0[c] * wa1 + v1[c] * wb1 + v2[c] * wc1 + v3[c] * wd1;
            }
        }
        for (; jj <= jhi; jj++) {
            f32x4 v = *(const f32x4*)(vbase + (size_t)jj * DD);
            float w0 = wgt2[jj][tok0], w1 = wgt2[jj][tok1];
            #pragma unroll
            for (int c = 0; c < 4; c++) {
                acc0[c] += v[c] * w0;
                acc1[c] += v[c] * w1;
            }
        }
        f32x4 u[2]; f32x4 ac[2]; ac[0] = acc0; ac[1] = acc1;
        #pragma unroll
        for (int ti = 0; ti < 2; ti++) {
            int tok = tg * 2 + ti;
            int n = n0 + tok;
            f32x4 vold = (f32x4)(0.f);
            if (n < NN) vold = *(const f32x4*)(val_in + ((size_t)(b * NN + n)) * DD + d);
            u[ti] = vold + ac[ti];
            float s = u[ti][0]*u[ti][0] + u[ti][1]*u[ti][1] + u[ti][2]*u[ti][2] + u[ti][3]*u[ti][3];
            float mb = fmaxf(fmaxf(fabsf(ac[ti][0]), fabsf(ac[ti][1])),
                             fmaxf(fabsf(ac[ti][2]), fabsf(ac[ti][3])));
            for (int off = 4; off <= 32; off <<= 1) {
                s += __shfl_xor(s, off, 64);
                mb = fmaxf(mb, __shfl_xor(mb, off, 64));
            }
            if ((l >> 2) == 0) { redS[tok][w] = s; redM[tok][w] = mb; }
        }
        __syncthreads();
        #pragma unroll
        for (int ti = 0; ti < 2; ti++) {
            int tok = tg * 2 + ti;
            int n = n0 + tok;
            if (n < NN) {
                float ss = redS[tok][0] + redS[tok][1] + redS[tok][2] + redS[tok][3];
                float mab = fmaxf(fmaxf(redM[tok][0], redM[tok][1]),
                                  fmaxf(redM[tok][2], redM[tok][3]));
                float rn = 1.f / fmaxf(sqrtf(ss), EPSF);
                f32x4 o = u[ti];
                if (mab > 0.f) { o[0] *= rn; o[1] *= rn; o[2] *= rn; o[3] *= rn; }
                size_t oi = ((size_t)(b * NN + n)) * DD + d;
                *(f32x4*)(val_out + oi) = o;
                ushort4 hv, mv;
                {
                    ushort h0 = f2b(o[0]); hv.x = h0; mv.x = f2b(o[0] - b2f(h0));
                    ushort h1 = f2b(o[1]); hv.y = h1; mv.y = f2b(o[1] - b2f(h1));
                    ushort h2 = f2b(o[2]); hv.z = h2; mv.z = f2b(o[2] - b2f(h2));
                    ushort h3 = f2b(o[3]); hv.w = h3; mv.w = f2b(o[3] - b2f(h3));
                }
                *(ushort4*)(vbH + oi) = hv;
                *(ushort4*)(vbM + oi) = mv;
            }
        }
    }
}

// ---------- state update ----------
__global__ void state_kernel(const float* __restrict__ state_in,
                             const float* __restrict__ dstate,
                             float* __restrict__ state_out) {
    __shared__ float xs[NN];
    __shared__ float redA[16];
    __shared__ float redB[16];
    int b = blockIdx.x, t = threadIdx.x;
    float lmax = -INFINITY;
    for (int n = t; n < NN; n += 1024) {
        float x = state_in[b * NN + n] + dstate[b * NN + n];
        xs[n] = x;
        lmax = fmaxf(lmax, fabsf(x));
    }
    lmax = wave_max(lmax);
    if ((t & 63) == 0) redA[t >> 6] = lmax;
    __syncthreads();
    float m = redA[0];
    #pragma unroll
    for (int i = 1; i < 16; i++) m = fmaxf(m, redA[i]);
    float lsum = 0.f;
    for (int n = t; n < NN; n += 1024) lsum += expf(fabsf(xs[n]) - m);
    lsum = wave_sum(lsum);
    if ((t & 63) == 0) redB[t >> 6] = lsum;
    __syncthreads();
    float ssum = 0.f;
    #pragma unroll
    for (int i = 0; i < 16; i++) ssum += redB[i];
    float inv = 1.f / ssum;
    for (int n = t; n < NN; n += 1024) {
        float x = xs[n];
        state_out[b * NN + n] = sgnf(x) * expf(fabsf(x) - m) * inv;
    }
}

// ---------- FFN: bf16x3 MFMA, 8-token blocks, A upfront ----------
__global__ __launch_bounds__(256, 2)
void ffn_kernel(const ushort* __restrict__ XbH, const ushort* __restrict__ XbM,
                const float*  __restrict__ Xf,
                const ushort* __restrict__ W1h, const ushort* __restrict__ W1l,
                const float*  __restrict__ b1,
                const ushort* __restrict__ W2h, const ushort* __restrict__ W2l,
                const float*  __restrict__ b2,
                float* __restrict__ val_out,
                ushort* __restrict__ o0, ushort* __restrict__ o1,
                ushort* __restrict__ o2) {
    __shared__ ushort HtH[8 * 520];   // 8.3 KB
    __shared__ ushort HtL[8 * 520];   // 8.3 KB
    __shared__ float red[8][33];
    __shared__ float rrn[8];
    float* Yt = (float*)HtH;          // reuse after GEMM2 (8*257*4 <= 8*520*2)

    int t = threadIdx.x;
    int w = t >> 6, l = t & 63;
    int m0 = blockIdx.x * 8;
    int lm = l & 15;
    int lk = (l >> 4) << 3;
    int cm = (l >> 4) << 2;
    int quad = l >> 4;

    // ---- GEMM1: X(8x256)@W1(256x512), wave w -> n in [128w,128w+128)
    int arow = m0 + (lm & 7); if (arow > MM - 1) arow = MM - 1;
    const ushort* ah_base = XbH + (size_t)arow * DD + lk;
    const ushort* al_base = XbM + (size_t)arow * DD + lk;
    bf16x8 afh[8], afl[8];
    #pragma unroll
    for (int kt = 0; kt < 8; kt++) {
        afh[kt] = *(const bf16x8*)(ah_base + kt * 32);
        afl[kt] = *(const bf16x8*)(al_base + kt * 32);
    }
    f32x4 acc[8];
    #pragma unroll
    for (int i = 0; i < 8; i++) acc[i] = (f32x4)(0.f);
    #pragma unroll
    for (int kt = 0; kt < 8; kt++) {
        size_t cb = (((size_t)kt * 32 + w * 8) * 64 + l) * 8;
        bf16x8 bh[8], bl[8];
        #pragma unroll
        for (int n = 0; n < 8; n++) {
            bh[n] = *(const bf16x8*)(W1h + cb + (size_t)n * 512);
            bl[n] = *(const bf16x8*)(W1l + cb + (size_t)n * 512);
        }
        #pragma unroll
        for (int n = 0; n < 8; n++) {
            acc[n] = __builtin_amdgcn_mfma_f32_16x16x32_bf16(afh[kt], bh[n], acc[n], 0, 0, 0);
            acc[n] = __builtin_amdgcn_mfma_f32_16x16x32_bf16(afl[kt], bh[n], acc[n], 0, 0, 0);
            acc[n] = __builtin_amdgcn_mfma_f32_16x16x32_bf16(afh[kt], bl[n], acc[n], 0, 0, 0);
        }
    }
    if (quad < 2) {
        #pragma unroll
        for (int n = 0; n < 8; n++) {
            int gn = w * 128 + n * 16 + lm;
            float bb = b1[gn];
            #pragma unroll
            for (int r = 0; r < 4; r++) {
                float x = acc[n][r] + bb;
                float g = 0.5f * x * (1.f + erff(x * 0.70710678118654752f));
                ushort gh = f2b(g);
                HtH[(cm + r) * 520 + gn] = gh;
                HtL[(cm + r) * 520 + gn] = f2b(g - b2f(gh));
            }
        }
    }
    __syncthreads();

    // ---- GEMM2: H(8x512)@W2(512x256), wave w -> n in [64w,64w+64)
    int hrow = lm & 7;
    f32x4 acc2[4];
    #pragma unroll
    for (int i = 0; i < 4; i++) acc2[i] = (f32x4)(0.f);
    #pragma unroll
    for (int kt = 0; kt < 16; kt++) {
        size_t cb = (((size_t)kt * 16 + w * 4) * 64 + l) * 8;
        bf16x8 b2h[4], b2l[4];
        #pragma unroll
        for (int n = 0; n < 4; n++) {
            b2h[n] = *(const bf16x8*)(W2h + cb + (size_t)n * 512);
            b2l[n] = *(const bf16x8*)(W2l + cb + (size_t)n * 512);
        }
        bf16x8 afh2 = *(const bf16x8*)(HtH + hrow * 520 + kt * 32 + lk);
        bf16x8 afl2 = *(const bf16x8*)(HtL + hrow * 520 + kt * 32 + lk);
        #pragma unroll
        for (int n = 0; n < 4; n++) {
            acc2[n] = __builtin_amdgcn_mfma_f32_16x16x32_bf16(afh2, b2h[n], acc2[n], 0, 0, 0);
            acc2[n] = __builtin_amdgcn_mfma_f32_16x16x32_bf16(afl2, b2h[n], acc2[n], 0, 0, 0);
            acc2[n] = __builtin_amdgcn_mfma_f32_16x16x32_bf16(afh2, b2l[n], acc2[n], 0, 0, 0);
        }
    }
    __syncthreads();   // done with Ht; reuse as Yt

    if (quad < 2) {
        #pragma unroll
        for (int n = 0; n < 4; n++) {
            int gn = w * 64 + n * 16 + lm;
            float bb = b2[gn];
            #pragma unroll
            for (int r = 0; r < 4; r++) {
                int row = m0 + cm + r;
                float xv = (row < MM) ? Xf[(size_t)row * DD + gn] : 0.f;
                Yt[(cm + r) * 257 + gn] = xv + acc2[n][r] + bb;
            }
        }
    }
    __syncthreads();
    {
        int m = t & 7, p = t >> 3;       // 8 tokens x 32 partials of 8
        float s = 0.f;
        #pragma unroll
        for (int i = 0; i < 8; i++) { float y = Yt[m * 257 + p * 8 + i]; s += y * y; }
        red[m][p] = s;
    }
    __syncthreads();
    if (t < 8) {
        float s = 0.f;
        #pragma unroll
        for (int i = 0; i < 32; i++) s += red[t][i];
        rrn[t] = 1.f / fmaxf(sqrtf(s), EPSF);
    }
    __syncthreads();
    #pragma unroll
    for (int m = 0; m < 8; m++) {
        int row = m0 + m;
        if (row < MM) {
            float o = Yt[m * 257 + t] * rrn[m];
            size_t oi = (size_t)row * DD + t;
            val_out[oi] = o;
            ushort h, mm, lo;
            split3(o, h, mm, lo);
            o0[oi] = h; o1[oi] = mm; o2[oi] = lo;
        }
    }
}

extern "C" void kernel_launch(void* const* d_in, const int* in_sizes, int n_in,
                              void* d_out, int out_size, void* d_ws, size_t ws_size,
                              hipStream_t stream) {
    const int*   ids          = (const int*)d_in[0];
    const float* emb          = (const float*)d_in[1];
    const float* pos          = (const float*)d_in[2];
    const float* anchor_val   = (const float*)d_in[3];
    const float* anchor_state = (const float*)d_in[4];
    const float* Ws           = (const float*)d_in[5];
    const float* bs           = (const float*)d_in[6];
    const float* U            = (const float*)d_in[7];
    const float* V            = (const float*)d_in[8];
    const float* W1           = (const float*)d_in[9];
    const float* b1           = (const float*)d_in[10];
    const float* W2           = (const float*)d_in[11];
    const float* b2           = (const float*)d_in[12];
    float* out = (float*)d_out;

    ushort* p = (ushort*)d_ws;
    ushort* vA0 = p; p += (size_t)MM * DD;
    ushort* vA1 = p; p += (size_t)MM * DD;
    ushort* vA2 = p; p += (size_t)MM * DD;
    ushort* vB0 = p; p += (size_t)MM * DD;
    ushort* vB1 = p; p += (size_t)MM * DD;
    ushort* q0b = p; p += (size_t)MM * HR;
    ushort* q1b = p; p += (size_t)MM * HR;
    ushort* q2b = p; p += (size_t)MM * HR;
    ushort* k0b = p; p += (size_t)MM * HR;
    ushort* k1b = p; p += (size_t)MM * HR;
    ushort* k2b = p; p += (size_t)MM * HR;
    ushort* W1ph = p; p += 3 * 131072;
    ushort* W1pl = p; p += 3 * 131072;
    ushort* W2ph = p; p += 3 * 131072;
    ushort* W2pl = p; p += 3 * 131072;
    ushort* U0p = p; p += 3 * 32768;
    ushort* U1p = p; p += 3 * 32768;
    ushort* U2p = p; p += 3 * 32768;
    ushort* V0p = p; p += 3 * 32768;
    ushort* V1p = p; p += 3 * 32768;
    ushort* V2p = p; p += 3 * 32768;
    float* f = (float*)p;
    float* valA = f; f += (size_t)MM * DD;
    float* valB = f; f += (size_t)MM * DD;
    float* st0  = f; f += MM;
    float* st1  = f; f += MM;
    float* dst  = f; f += MM;

    packall_kernel<<<3840, 256, 0, stream>>>(W1, W2, U, V,
                                             W1ph, W1pl, W2ph, W2pl,
                                             U0p, U1p, U2p, V0p, V1p, V2p);

    embed_kernel<<<MM, 256, 0, stream>>>(ids, emb, pos, anchor_val, anchor_state,
                                         Ws, bs, valA, vA0, vA1, vA2, st0);
    float* s_in = st0;
    float* s_out = st1;
    for (int l = 0; l < 3; l++) {
        proj_kernel<<<(MM + 7) / 8, 256, 0, stream>>>(
            vA0, vA1, vA2,
            U0p + (size_t)l * 32768, U1p + (size_t)l * 32768, U2p + (size_t)l * 32768,
            V0p + (size_t)l * 32768, V1p + (size_t)l * 32768, V2p + (size_t)l * 32768,
            q0b, q1b, q2b, k0b, k1b, k2b);
        attn_kernel<<<BB * TB8, 256, 0, stream>>>(valA, s_in,
                                                  q0b, q1b, q2b, k0b, k1b, k2b,
                                                  valB, vB0, vB1, dst);
        state_kernel<<<BB, 1024, 0, stream>>>(s_in, dst, (l == 2) ? out : s_out);
        ffn_kernel<<<(MM + 7) / 8, 256, 0, stream>>>(
            vB0, vB1, valB,
            W1ph + (size_t)l * 131072, W1pl + (size_t)l * 131072, b1 + (size_t)l * DFF,
            W2ph + (size_t)l * 131072, W2pl + (size_t)l * 131072, b2 + (size_t)l * DD,
            (l == 2) ? (out + MM) : valA, vA0, vA1, vA2);
        float* tmp = s_in; s_in = s_out; s_out = tmp;
    }
}

// Round 9
// 387.665 us; speedup vs baseline: 1.1942x; 1.0750x over previous
//
#include <hip/hip_runtime.h>
#include <hip/hip_bf16.h>
#include <math.h>

#define BB 2
#define SS 2048
#define NN 2049
#define MM (BB*NN)      // 4098 rows
#define DD 256
#define HR 128          // HEADS*RANK
#define NHEAD 4
#define WINW 64
#define DFF 512
#define EPSF 1e-6f
#define TB8 257         // ceil(NN/8) attn tiles per batch

typedef __attribute__((ext_vector_type(8))) short bf16x8;
typedef __attribute__((ext_vector_type(4))) float f32x4;

// ---------- helpers ----------
__device__ __forceinline__ float wave_sum(float v) {
    v += __shfl_down(v, 32, 64); v += __shfl_down(v, 16, 64);
    v += __shfl_down(v, 8, 64);  v += __shfl_down(v, 4, 64);
    v += __shfl_down(v, 2, 64);  v += __shfl_down(v, 1, 64);
    return v;
}
__device__ __forceinline__ float wave_max(float v) {
    v = fmaxf(v, __shfl_down(v, 32, 64)); v = fmaxf(v, __shfl_down(v, 16, 64));
    v = fmaxf(v, __shfl_down(v, 8, 64));  v = fmaxf(v, __shfl_down(v, 4, 64));
    v = fmaxf(v, __shfl_down(v, 2, 64));  v = fmaxf(v, __shfl_down(v, 1, 64));
    return v;
}
__device__ __forceinline__ float block_sum(float v, float* red) {
    v = wave_sum(v);
    __syncthreads();
    if ((threadIdx.x & 63) == 0) red[threadIdx.x >> 6] = v;
    __syncthreads();
    return red[0] + red[1] + red[2] + red[3];
}
__device__ __forceinline__ float sgnf(float x) {
    return (x > 0.f) ? 1.f : ((x < 0.f) ? -1.f : 0.f);
}
__device__ __forceinline__ ushort f2b(float x) {
    __hip_bfloat16 h = __float2bfloat16(x);
    return *(ushort*)&h;
}
__device__ __forceinline__ float b2f(ushort u) {
    unsigned int v = ((unsigned int)u) << 16;
    return *(float*)&v;
}
__device__ __forceinline__ void split3(float x, ushort& h, ushort& m, ushort& l) {
    h = f2b(x);
    float r1 = x - b2f(h);
    m = f2b(r1);
    l = f2b(r1 - b2f(m));
}
__device__ __forceinline__ void pack_map(int e, int N, int& k, int& n) {
    int j = e & 7;
    int l = (e >> 3) & 63;
    int c = e >> 9;
    int ntiles = N >> 4;
    int kt = c / ntiles, nt = c - kt * ntiles;
    k = kt * 32 + ((l >> 4) << 3) + j;
    n = nt * 16 + (l & 15);
}
// async global->LDS DMA, 16B per lane; lds dest = base + lane*16
__device__ __forceinline__ void dma16(const ushort* g, ushort* lds) {
    __builtin_amdgcn_global_load_lds(
        (const __attribute__((address_space(1))) unsigned int*)g,
        (__attribute__((address_space(3))) unsigned int*)lds,
        16, 0, 0);
}

// ---------- fused weight pack ----------
__global__ void packall_kernel(const float* __restrict__ W1, const float* __restrict__ W2,
                               const float* __restrict__ U,  const float* __restrict__ V,
                               ushort* __restrict__ W1ph, ushort* __restrict__ W1pl,
                               ushort* __restrict__ W2ph, ushort* __restrict__ W2pl,
                               ushort* __restrict__ U0, ushort* __restrict__ U1,
                               ushort* __restrict__ U2,
                               ushort* __restrict__ V0, ushort* __restrict__ V1,
                               ushort* __restrict__ V2) {
    int idx = blockIdx.x * 256 + threadIdx.x;
    int l = idx / 327680;
    int r = idx - l * 327680;
    if (l >= 3) return;
    int k, n;
    if (r < 131072) {
        int e = r;
        pack_map(e, 512, k, n);
        float s = W1[(size_t)l * 131072 + (size_t)k * 512 + n];
        ushort h = f2b(s);
        W1ph[(size_t)l * 131072 + e] = h;
        W1pl[(size_t)l * 131072 + e] = f2b(s - b2f(h));
    } else if (r < 262144) {
        int e = r - 131072;
        pack_map(e, 256, k, n);
        float s = W2[(size_t)l * 131072 + (size_t)k * 256 + n];
        ushort h = f2b(s);
        W2ph[(size_t)l * 131072 + e] = h;
        W2pl[(size_t)l * 131072 + e] = f2b(s - b2f(h));
    } else if (r < 294912) {
        int e = r - 262144;
        pack_map(e, 128, k, n);
        ushort h, m, lo;
        split3(U[(size_t)l * 32768 + (size_t)k * 128 + n], h, m, lo);
        U0[(size_t)l * 32768 + e] = h;
        U1[(size_t)l * 32768 + e] = m;
        U2[(size_t)l * 32768 + e] = lo;
    } else {
        int e = r - 294912;
        pack_map(e, 128, k, n);
        ushort h, m, lo;
        split3(V[(size_t)l * 32768 + (size_t)k * 128 + n], h, m, lo);
        V0[(size_t)l * 32768 + e] = h;
        V1[(size_t)l * 32768 + e] = m;
        V2[(size_t)l * 32768 + e] = lo;
    }
}

// ---------- embed ----------
__global__ void embed_kernel(const int* __restrict__ ids,
                             const float* __restrict__ emb,
                             const float* __restrict__ pos,
                             const float* __restrict__ anchor_val,
                             const float* __restrict__ anchor_state,
                             const float* __restrict__ Ws,
                             const float* __restrict__ bs,
                             float* __restrict__ val,
                             ushort* __restrict__ v0, ushort* __restrict__ v1,
                             ushort* __restrict__ v2,
                             float* __restrict__ state) {
    __shared__ float red[4];
    int row = blockIdx.x;
    int t = threadIdx.x;
    int b = row / NN, n = row % NN;
    float e;
    if (n == 0) {
        e = anchor_val[t];
    } else {
        int id = ids[b * SS + (n - 1)];
        e = emb[(size_t)id * DD + t] + pos[(size_t)(n - 1) * DD + t];
    }
    float ss = block_sum(e * e, red);
    float ts = block_sum(e * Ws[t], red);
    float rn = 1.f / fmaxf(sqrtf(ss), EPSF);
    float o = e * rn;
    size_t oi = (size_t)row * DD + t;
    val[oi] = o;
    ushort h, m, lo;
    split3(o, h, m, lo);
    v0[oi] = h; v1[oi] = m; v2[oi] = lo;
    if (t == 0) state[row] = (n == 0) ? anchor_state[0] : (ts + bs[0]);
}

// ---------- proj: 6-term MFMA, T=32, q|k per block, DMA-staged weights ----------
__global__ __launch_bounds__(256, 2)
void proj_kernel(const ushort* __restrict__ X0, const ushort* __restrict__ X1,
                 const ushort* __restrict__ X2,
                 const ushort* __restrict__ U0, const ushort* __restrict__ U1,
                 const ushort* __restrict__ U2,
                 const ushort* __restrict__ V0, const ushort* __restrict__ V1,
                 const ushort* __restrict__ V2,
                 ushort* __restrict__ q0, ushort* __restrict__ q1,
                 ushort* __restrict__ q2,
                 ushort* __restrict__ k0, ushort* __restrict__ k1,
                 ushort* __restrict__ k2) {
    __shared__ __align__(16) ushort stage[2][24 * 512];   // 48 KB
    int t = threadIdx.x;
    int w = t >> 6, l = t & 63;
    int lm = l & 15, quad = l >> 4;
    int m0 = blockIdx.x * 32;
    bool isQ = (blockIdx.y == 0);
    const ushort* P0 = isQ ? U0 : V0;
    const ushort* P1 = isQ ? U1 : V1;
    const ushort* P2 = isQ ? U2 : V2;
    const ushort* P[3] = {P0, P1, P2};
    int row0 = m0 + lm;      if (row0 > MM - 1) row0 = MM - 1;
    int row1 = m0 + 16 + lm; if (row1 > MM - 1) row1 = MM - 1;

    // preload kt=0: 24 chunks (3 planes x 8 ntiles), wave w does 6
    #pragma unroll
    for (int i = 0; i < 6; i++) {
        int c = w * 6 + i;
        int p = c >> 3, ntl = c & 7;
        dma16(P[p] + ((size_t)(0 * 8 + ntl) * 64 + l) * 8,
              &stage[0][c * 512 + l * 8]);
    }
    __syncthreads();

    f32x4 acc[2][2];
    #pragma unroll
    for (int mi = 0; mi < 2; mi++)
        #pragma unroll
        for (int jj = 0; jj < 2; jj++) acc[mi][jj] = (f32x4)(0.f);

    for (int kt = 0; kt < 8; kt++) {
        int cur = kt & 1;
        if (kt < 7) {
            #pragma unroll
            for (int i = 0; i < 6; i++) {
                int c = w * 6 + i;
                int p = c >> 3, ntl = c & 7;
                dma16(P[p] + ((size_t)((kt + 1) * 8 + ntl) * 64 + l) * 8,
                      &stage[cur ^ 1][c * 512 + l * 8]);
            }
        }
        int ko = kt * 32 + quad * 8;
        bf16x8 a0[2], a1[2], a2[2];
        a0[0] = *(const bf16x8*)(X0 + (size_t)row0 * DD + ko);
        a1[0] = *(const bf16x8*)(X1 + (size_t)row0 * DD + ko);
        a2[0] = *(const bf16x8*)(X2 + (size_t)row0 * DD + ko);
        a0[1] = *(const bf16x8*)(X0 + (size_t)row1 * DD + ko);
        a1[1] = *(const bf16x8*)(X1 + (size_t)row1 * DD + ko);
        a2[1] = *(const bf16x8*)(X2 + (size_t)row1 * DD + ko);
        #pragma unroll
        for (int jj = 0; jj < 2; jj++) {
            int ntl = w * 2 + jj;
            bf16x8 b0 = *(const bf16x8*)&stage[cur][(0 * 8 + ntl) * 512 + l * 8];
            bf16x8 b1 = *(const bf16x8*)&stage[cur][(1 * 8 + ntl) * 512 + l * 8];
            bf16x8 b2 = *(const bf16x8*)&stage[cur][(2 * 8 + ntl) * 512 + l * 8];
            #pragma unroll
            for (int mi = 0; mi < 2; mi++) {
                acc[mi][jj] = __builtin_amdgcn_mfma_f32_16x16x32_bf16(a0[mi], b0, acc[mi][jj], 0, 0, 0);
                acc[mi][jj] = __builtin_amdgcn_mfma_f32_16x16x32_bf16(a0[mi], b1, acc[mi][jj], 0, 0, 0);
                acc[mi][jj] = __builtin_amdgcn_mfma_f32_16x16x32_bf16(a1[mi], b0, acc[mi][jj], 0, 0, 0);
                acc[mi][jj] = __builtin_amdgcn_mfma_f32_16x16x32_bf16(a1[mi], b1, acc[mi][jj], 0, 0, 0);
                acc[mi][jj] = __builtin_amdgcn_mfma_f32_16x16x32_bf16(a0[mi], b2, acc[mi][jj], 0, 0, 0);
                acc[mi][jj] = __builtin_amdgcn_mfma_f32_16x16x32_bf16(a2[mi], b0, acc[mi][jj], 0, 0, 0);
            }
        }
        __syncthreads();
    }
    ushort* o0 = isQ ? q0 : k0;
    ushort* o1 = isQ ? q1 : k1;
    ushort* o2 = isQ ? q2 : k2;
    #pragma unroll
    for (int mi = 0; mi < 2; mi++) {
        #pragma unroll
        for (int jj = 0; jj < 2; jj++) {
            int n = (w * 2 + jj) * 16 + lm;
            #pragma unroll
            for (int r = 0; r < 4; r++) {
                int tok = m0 + mi * 16 + quad * 4 + r;
                if (tok < MM) {
                    ushort h, m, lo;
                    split3(acc[mi][jj][r], h, m, lo);
                    size_t oi = (size_t)tok * HR + n;
                    o0[oi] = h; o1[oi] = m; o2[oi] = lo;
                }
            }
        }
    }
}

// ---------- attention (round-8 version, unchanged) ----------
__global__ __launch_bounds__(256, 2)
void attn_kernel(const float* __restrict__ val_in,
                 const float* __restrict__ state_in,
                 const ushort* __restrict__ q0, const ushort* __restrict__ q1,
                 const ushort* __restrict__ q2,
                 const ushort* __restrict__ k0, const ushort* __restrict__ k1,
                 const ushort* __restrict__ k2,
                 float* __restrict__ val_out,
                 ushort* __restrict__ vbH, ushort* __restrict__ vbM,
                 float* __restrict__ dstate_out) {
    __shared__ float sc4[NHEAD][8][148];
    __shared__ float wgt2[144][12];
    __shared__ float redS[8][4];
    __shared__ float redM[8][4];

    int b = blockIdx.x / TB8;
    int n0 = (blockIdx.x % TB8) * 8;
    int t = threadIdx.x;
    int w = t >> 6, l = t & 63;
    int lm = l & 15, quad = l >> 4;

    {
        int qrow = n0 + (lm & 7);
        if (qrow > NN - 1) qrow = NN - 1;
        size_t qa = ((size_t)(b * NN + qrow)) * HR + w * 32 + quad * 8;
        bf16x8 a0 = *(const bf16x8*)(q0 + qa);
        bf16x8 a1 = *(const bf16x8*)(q1 + qa);
        bf16x8 a2 = *(const bf16x8*)(q2 + qa);
        bf16x8 kf0[9], kf1[9], kf2[9];
        #pragma unroll
        for (int jt = 0; jt < 9; jt++) {
            int j = n0 - 64 + jt * 16 + lm;
            j = (j < 0) ? 0 : ((j > NN - 1) ? NN - 1 : j);
            size_t ka = ((size_t)(b * NN + j)) * HR + w * 32 + quad * 8;
            kf0[jt] = *(const bf16x8*)(k0 + ka);
            kf1[jt] = *(const bf16x8*)(k1 + ka);
            kf2[jt] = *(const bf16x8*)(k2 + ka);
        }
        #pragma unroll
        for (int jt = 0; jt < 9; jt++) {
            f32x4 acc = (f32x4)(0.f);
            acc = __builtin_amdgcn_mfma_f32_16x16x32_bf16(a0, kf0[jt], acc, 0, 0, 0);
            acc = __builtin_amdgcn_mfma_f32_16x16x32_bf16(a0, kf1[jt], acc, 0, 0, 0);
            acc = __builtin_amdgcn_mfma_f32_16x16x32_bf16(a1, kf0[jt], acc, 0, 0, 0);
            acc = __builtin_amdgcn_mfma_f32_16x16x32_bf16(a1, kf1[jt], acc, 0, 0, 0);
            acc = __builtin_amdgcn_mfma_f32_16x16x32_bf16(a0, kf2[jt], acc, 0, 0, 0);
            acc = __builtin_amdgcn_mfma_f32_16x16x32_bf16(a2, kf0[jt], acc, 0, 0, 0);
            if (quad < 2) {
                #pragma unroll
                for (int r = 0; r < 4; r++)
                    sc4[w][quad * 4 + r][jt * 16 + lm] = acc[r];
            }
        }
    }
    __syncthreads();

    {
        int m = t >> 5, p = t & 31;
        int n = n0 + m;
        bool tokv = (n < NN);
        float sv[5]; bool vv[5];
        float mx = -INFINITY;
        #pragma unroll
        for (int i = 0; i < 5; i++) {
            int tap = p + 32 * i;
            bool inb = (tap < 144);
            int tapc = inb ? tap : 0;
            int j = n0 - 64 + tapc;
            float s0 = sc4[0][m][tapc], s1 = sc4[1][m][tapc];
            float s2 = sc4[2][m][tapc], s3 = sc4[3][m][tapc];
            float s = fmaxf(fmaxf(s0, s1), fmaxf(s2, s3)) * 0.17677669529663687f;
            bool v = inb && tokv && (tap >= m) && (tap <= m + 128) && (j >= 0) && (j < NN);
            sv[i] = s; vv[i] = v;
            if (v) mx = fmaxf(mx, fabsf(s));
        }
        for (int off = 16; off > 0; off >>= 1) mx = fmaxf(mx, __shfl_xor(mx, off, 64));
        float ee[5];
        float sum = 0.f;
        #pragma unroll
        for (int i = 0; i < 5; i++) {
            ee[i] = vv[i] ? expf(fabsf(sv[i]) - mx) : 0.f;
            sum += ee[i];
        }
        for (int off = 16; off > 0; off >>= 1) sum += __shfl_xor(sum, off, 64);
        float inv = (sum > 0.f) ? 1.f / sum : 0.f;
        float ds = 0.f;
        #pragma unroll
        for (int i = 0; i < 5; i++) {
            int tap = p + 32 * i;
            if (tap < 144) {
                float wg = vv[i] ? sgnf(sv[i]) * ee[i] * inv : 0.f;
                wgt2[tap][m] = wg;
                if (vv[i]) ds += wg * state_in[b * NN + (n0 - 64 + tap)];
            }
        }
        for (int off = 16; off > 0; off >>= 1) ds += __shfl_xor(ds, off, 64);
        if (p == 0 && tokv) dstate_out[b * NN + n] = ds;
    }
    __syncthreads();

    {
        int d = (t >> 2) * 4;
        int tg = t & 3;
        int tok0 = tg * 2, tok1 = tg * 2 + 1;
        int jlo = (n0 >= 64) ? 0 : (64 - n0);
        int jhi = NN - 1 - n0 + 64; if (jhi > 135) jhi = 135;
        const float* vbase = val_in + ((size_t)(b * NN + n0 - 64)) * DD + d;
        f32x4 acc0 = (f32x4)(0.f), acc1 = (f32x4)(0.f);
        int jj = jlo;
        for (; jj + 3 <= jhi; jj += 4) {
            f32x4 v0 = *(const f32x4*)(vbase + (size_t)(jj + 0) * DD);
            f32x4 v1 = *(const f32x4*)(vbase + (size_t)(jj + 1) * DD);
            f32x4 v2 = *(const f32x4*)(vbase + (size_t)(jj + 2) * DD);
            f32x4 v3 = *(const f32x4*)(vbase + (size_t)(jj + 3) * DD);
            float wa0 = wgt2[jj + 0][tok0], wa1 = wgt2[jj + 0][tok1];
            float wb0 = wgt2[jj + 1][tok0], wb1 = wgt2[jj + 1][tok1];
            float wc0 = wgt2[jj + 2][tok0], wc1 = wgt2[jj + 2][tok1];
            float wd0 = wgt2[jj + 3][tok0], wd1 = wgt2[jj + 3][tok1];
            #pragma unroll
            for (int c = 0; c < 4; c++) {
                acc0[c] += v0[c] * wa0 + v1[c] * wb0 + v2[c] * wc0 + v3[c] * wd0;
                acc1[c] += v0[c] * wa1 + v1[c] * wb1 + v2[c] * wc1 + v3[c] * wd1;
            }
        }
        for (; jj <= jhi; jj++) {
            f32x4 v = *(const f32x4*)(vbase + (size_t)jj * DD);
            float w0 = wgt2[jj][tok0], w1 = wgt2[jj][tok1];
            #pragma unroll
            for (int c = 0; c < 4; c++) {
                acc0[c] += v[c] * w0;
                acc1[c] += v[c] * w1;
            }
        }
        f32x4 u[2]; f32x4 ac[2]; ac[0] = acc0; ac[1] = acc1;
        #pragma unroll
        for (int ti = 0; ti < 2; ti++) {
            int tok = tg * 2 + ti;
            int n = n0 + tok;
            f32x4 vold = (f32x4)(0.f);
            if (n < NN) vold = *(const f32x4*)(val_in + ((size_t)(b * NN + n)) * DD + d);
            u[ti] = vold + ac[ti];
            float s = u[ti][0]*u[ti][0] + u[ti][1]*u[ti][1] + u[ti][2]*u[ti][2] + u[ti][3]*u[ti][3];
            float mb = fmaxf(fmaxf(fabsf(ac[ti][0]), fabsf(ac[ti][1])),
                             fmaxf(fabsf(ac[ti][2]), fabsf(ac[ti][3])));
            for (int off = 4; off <= 32; off <<= 1) {
                s += __shfl_xor(s, off, 64);
                mb = fmaxf(mb, __shfl_xor(mb, off, 64));
            }
            if ((l >> 2) == 0) { redS[tok][w] = s; redM[tok][w] = mb; }
        }
        __syncthreads();
        #pragma unroll
        for (int ti = 0; ti < 2; ti++) {
            int tok = tg * 2 + ti;
            int n = n0 + tok;
            if (n < NN) {
                float ss = redS[tok][0] + redS[tok][1] + redS[tok][2] + redS[tok][3];
                float mab = fmaxf(fmaxf(redM[tok][0], redM[tok][1]),
                                  fmaxf(redM[tok][2], redM[tok][3]));
                float rn = 1.f / fmaxf(sqrtf(ss), EPSF);
                f32x4 o = u[ti];
                if (mab > 0.f) { o[0] *= rn; o[1] *= rn; o[2] *= rn; o[3] *= rn; }
                size_t oi = ((size_t)(b * NN + n)) * DD + d;
                *(f32x4*)(val_out + oi) = o;
                ushort4 hv, mv;
                {
                    ushort h0 = f2b(o[0]); hv.x = h0; mv.x = f2b(o[0] - b2f(h0));
                    ushort h1 = f2b(o[1]); hv.y = h1; mv.y = f2b(o[1] - b2f(h1));
                    ushort h2 = f2b(o[2]); hv.z = h2; mv.z = f2b(o[2] - b2f(h2));
                    ushort h3 = f2b(o[3]); hv.w = h3; mv.w = f2b(o[3] - b2f(h3));
                }
                *(ushort4*)(vbH + oi) = hv;
                *(ushort4*)(vbM + oi) = mv;
            }
        }
    }
}

// ---------- state update ----------
__global__ void state_kernel(const float* __restrict__ state_in,
                             const float* __restrict__ dstate,
                             float* __restrict__ state_out) {
    __shared__ float xs[NN];
    __shared__ float redA[16];
    __shared__ float redB[16];
    int b = blockIdx.x, t = threadIdx.x;
    float lmax = -INFINITY;
    for (int n = t; n < NN; n += 1024) {
        float x = state_in[b * NN + n] + dstate[b * NN + n];
        xs[n] = x;
        lmax = fmaxf(lmax, fabsf(x));
    }
    lmax = wave_max(lmax);
    if ((t & 63) == 0) redA[t >> 6] = lmax;
    __syncthreads();
    float m = redA[0];
    #pragma unroll
    for (int i = 1; i < 16; i++) m = fmaxf(m, redA[i]);
    float lsum = 0.f;
    for (int n = t; n < NN; n += 1024) lsum += expf(fabsf(xs[n]) - m);
    lsum = wave_sum(lsum);
    if ((t & 63) == 0) redB[t >> 6] = lsum;
    __syncthreads();
    float ssum = 0.f;
    #pragma unroll
    for (int i = 0; i < 16; i++) ssum += redB[i];
    float inv = 1.f / ssum;
    for (int n = t; n < NN; n += 1024) {
        float x = xs[n];
        state_out[b * NN + n] = sgnf(x) * expf(fabsf(x) - m) * inv;
    }
}

// ---------- ffn1: GEMM1 + gelu -> H hi/lo, T=32, N-half per block, staged ----------
__global__ __launch_bounds__(256, 2)
void ffn1_kernel(const ushort* __restrict__ XbH, const ushort* __restrict__ XbM,
                 const ushort* __restrict__ W1h, const ushort* __restrict__ W1l,
                 const float*  __restrict__ b1,
                 ushort* __restrict__ Hh, ushort* __restrict__ Hl) {
    __shared__ __align__(16) ushort stage[2][32 * 512];   // 64 KB
    int t = threadIdx.x;
    int w = t >> 6, l = t & 63;
    int lm = l & 15, quad = l >> 4;
    int m0 = blockIdx.x * 32;
    int nh = blockIdx.y;
    int row0 = m0 + lm;      if (row0 > MM - 1) row0 = MM - 1;
    int row1 = m0 + 16 + lm; if (row1 > MM - 1) row1 = MM - 1;

    #pragma unroll
    for (int i = 0; i < 8; i++) {
        int c = w * 8 + i;
        int p = c >> 4, ntl = c & 15;
        const ushort* src = (p ? W1l : W1h) + ((size_t)(0 * 32 + nh * 16 + ntl) * 64 + l) * 8;
        dma16(src, &stage[0][c * 512 + l * 8]);
    }
    __syncthreads();

    f32x4 acc[2][4];
    #pragma unroll
    for (int mi = 0; mi < 2; mi++)
        #pragma unroll
        for (int jj = 0; jj < 4; jj++) acc[mi][jj] = (f32x4)(0.f);

    for (int kt = 0; kt < 8; kt++) {
        int cur = kt & 1;
        if (kt < 7) {
            #pragma unroll
            for (int i = 0; i < 8; i++) {
                int c = w * 8 + i;
                int p = c >> 4, ntl = c & 15;
                const ushort* src = (p ? W1l : W1h) +
                    ((size_t)((kt + 1) * 32 + nh * 16 + ntl) * 64 + l) * 8;
                dma16(src, &stage[cur ^ 1][c * 512 + l * 8]);
            }
        }
        int ko = kt * 32 + quad * 8;
        bf16x8 ah[2], am[2];
        ah[0] = *(const bf16x8*)(XbH + (size_t)row0 * DD + ko);
        am[0] = *(const bf16x8*)(XbM + (size_t)row0 * DD + ko);
        ah[1] = *(const bf16x8*)(XbH + (size_t)row1 * DD + ko);
        am[1] = *(const bf16x8*)(XbM + (size_t)row1 * DD + ko);
        #pragma unroll
        for (int jj = 0; jj < 4; jj++) {
            int ntl = w * 4 + jj;
            bf16x8 bh = *(const bf16x8*)&stage[cur][ntl * 512 + l * 8];
            bf16x8 bl = *(const bf16x8*)&stage[cur][(16 + ntl) * 512 + l * 8];
            #pragma unroll
            for (int mi = 0; mi < 2; mi++) {
                acc[mi][jj] = __builtin_amdgcn_mfma_f32_16x16x32_bf16(ah[mi], bh, acc[mi][jj], 0, 0, 0);
                acc[mi][jj] = __builtin_amdgcn_mfma_f32_16x16x32_bf16(am[mi], bh, acc[mi][jj], 0, 0, 0);
                acc[mi][jj] = __builtin_amdgcn_mfma_f32_16x16x32_bf16(ah[mi], bl, acc[mi][jj], 0, 0, 0);
            }
        }
        __syncthreads();
    }
    #pragma unroll
    for (int mi = 0; mi < 2; mi++) {
        #pragma unroll
        for (int jj = 0; jj < 4; jj++) {
            int gn = nh * 256 + (w * 4 + jj) * 16 + lm;
            float bb = b1[gn];
            #pragma unroll
            for (int r = 0; r < 4; r++) {
                int tok = m0 + mi * 16 + quad * 4 + r;
                if (tok < MM) {
                    float x = acc[mi][jj][r] + bb;
                    float g = 0.5f * x * (1.f + erff(x * 0.70710678118654752f));
                    ushort gh = f2b(g);
                    size_t oi = (size_t)tok * DFF + gn;
                    Hh[oi] = gh;
                    Hl[oi] = f2b(g - b2f(gh));
                }
            }
        }
    }
}

// ---------- ffn2: GEMM2 + residual + bias -> Y (f32), T=32, N-half, staged ----------
__global__ __launch_bounds__(256, 2)
void ffn2_kernel(const ushort* __restrict__ Hh, const ushort* __restrict__ Hl,
                 const float*  __restrict__ Xf,
                 const ushort* __restrict__ W2h, const ushort* __restrict__ W2l,
                 const float*  __restrict__ b2,
                 float* __restrict__ Yb) {
    __shared__ __align__(16) ushort stage[2][16 * 512];   // 32 KB
    int t = threadIdx.x;
    int w = t >> 6, l = t & 63;
    int lm = l & 15, quad = l >> 4;
    int m0 = blockIdx.x * 32;
    int nh = blockIdx.y;
    int row0 = m0 + lm;      if (row0 > MM - 1) row0 = MM - 1;
    int row1 = m0 + 16 + lm; if (row1 > MM - 1) row1 = MM - 1;

    #pragma unroll
    for (int i = 0; i < 4; i++) {
        int c = w * 4 + i;
        int p = c >> 3, ntl = c & 7;
        const ushort* src = (p ? W2l : W2h) + ((size_t)(0 * 16 + nh * 8 + ntl) * 64 + l) * 8;
        dma16(src, &stage[0][c * 512 + l * 8]);
    }
    __syncthreads();

    f32x4 acc[2][2];
    #pragma unroll
    for (int mi = 0; mi < 2; mi++)
        #pragma unroll
        for (int jj = 0; jj < 2; jj++) acc[mi][jj] = (f32x4)(0.f);

    for (int kt = 0; kt < 16; kt++) {
        int cur = kt & 1;
        if (kt < 15) {
            #pragma unroll
            for (int i = 0; i < 4; i++) {
                int c = w * 4 + i;
                int p = c >> 3, ntl = c & 7;
                const ushort* src = (p ? W2l : W2h) +
                    ((size_t)((kt + 1) * 16 + nh * 8 + ntl) * 64 + l) * 8;
                dma16(src, &stage[cur ^ 1][c * 512 + l * 8]);
            }
        }
        int ko = kt * 32 + quad * 8;
        bf16x8 ah[2], al[2];
        ah[0] = *(const bf16x8*)(Hh + (size_t)row0 * DFF + ko);
        al[0] = *(const bf16x8*)(Hl + (size_t)row0 * DFF + ko);
        ah[1] = *(const bf16x8*)(Hh + (size_t)row1 * DFF + ko);
        al[1] = *(const bf16x8*)(Hl + (size_t)row1 * DFF + ko);
        #pragma unroll
        for (int jj = 0; jj < 2; jj++) {
            int ntl = w * 2 + jj;
            bf16x8 bh = *(const bf16x8*)&stage[cur][ntl * 512 + l * 8];
            bf16x8 bl = *(const bf16x8*)&stage[cur][(8 + ntl) * 512 + l * 8];
            #pragma unroll
            for (int mi = 0; mi < 2; mi++) {
                acc[mi][jj] = __builtin_amdgcn_mfma_f32_16x16x32_bf16(ah[mi], bh, acc[mi][jj], 0, 0, 0);
                acc[mi][jj] = __builtin_amdgcn_mfma_f32_16x16x32_bf16(al[mi], bh, acc[mi][jj], 0, 0, 0);
                acc[mi][jj] = __builtin_amdgcn_mfma_f32_16x16x32_bf16(ah[mi], bl, acc[mi][jj], 0, 0, 0);
            }
        }
        __syncthreads();
    }
    #pragma unroll
    for (int mi = 0; mi < 2; mi++) {
        #pragma unroll
        for (int jj = 0; jj < 2; jj++) {
            int gn = nh * 128 + (w * 2 + jj) * 16 + lm;
            float bb = b2[gn];
            #pragma unroll
            for (int r = 0; r < 4; r++) {
                int tok = m0 + mi * 16 + quad * 4 + r;
                if (tok < MM) {
                    size_t oi = (size_t)tok * DD + gn;
                    Yb[oi] = Xf[oi] + acc[mi][jj][r] + bb;
                }
            }
        }
    }
}

// ---------- ffn3: row norm + split3 ----------
__global__ void ffn3_kernel(const float* __restrict__ Yb,
                            float* __restrict__ val_out,
                            ushort* __restrict__ o0, ushort* __restrict__ o1,
                            ushort* __restrict__ o2) {
    int t = threadIdx.x;
    int w = t >> 6, l = t & 63;
    int row = blockIdx.x * 4 + w;
    if (row >= MM) return;
    f32x4 y = *(const f32x4*)(Yb + (size_t)row * DD + l * 4);
    float s = y[0]*y[0] + y[1]*y[1] + y[2]*y[2] + y[3]*y[3];
    #pragma unroll
    for (int off = 1; off < 64; off <<= 1) s += __shfl_xor(s, off, 64);
    float rn = 1.f / fmaxf(sqrtf(s), EPSF);
    f32x4 o;
    o[0] = y[0] * rn; o[1] = y[1] * rn; o[2] = y[2] * rn; o[3] = y[3] * rn;
    size_t oi = (size_t)row * DD + l * 4;
    *(f32x4*)(val_out + oi) = o;
    ushort4 h4, m4, l4;
    ushort hh, mm, ll;
    split3(o[0], hh, mm, ll); h4.x = hh; m4.x = mm; l4.x = ll;
    split3(o[1], hh, mm, ll); h4.y = hh; m4.y = mm; l4.y = ll;
    split3(o[2], hh, mm, ll); h4.z = hh; m4.z = mm; l4.z = ll;
    split3(o[3], hh, mm, ll); h4.w = hh; m4.w = mm; l4.w = ll;
    *(ushort4*)(o0 + oi) = h4;
    *(ushort4*)(o1 + oi) = m4;
    *(ushort4*)(o2 + oi) = l4;
}

extern "C" void kernel_launch(void* const* d_in, const int* in_sizes, int n_in,
                              void* d_out, int out_size, void* d_ws, size_t ws_size,
                              hipStream_t stream) {
    const int*   ids          = (const int*)d_in[0];
    const float* emb          = (const float*)d_in[1];
    const float* pos          = (const float*)d_in[2];
    const float* anchor_val   = (const float*)d_in[3];
    const float* anchor_state = (const float*)d_in[4];
    const float* Ws           = (const float*)d_in[5];
    const float* bs           = (const float*)d_in[6];
    const float* U            = (const float*)d_in[7];
    const float* V            = (const float*)d_in[8];
    const float* W1           = (const float*)d_in[9];
    const float* b1           = (const float*)d_in[10];
    const float* W2           = (const float*)d_in[11];
    const float* b2           = (const float*)d_in[12];
    float* out = (float*)d_out;

    ushort* p = (ushort*)d_ws;
    ushort* vA0 = p; p += (size_t)MM * DD;
    ushort* vA1 = p; p += (size_t)MM * DD;
    ushort* vA2 = p; p += (size_t)MM * DD;
    ushort* vB0 = p; p += (size_t)MM * DD;
    ushort* vB1 = p; p += (size_t)MM * DD;
    ushort* q0b = p; p += (size_t)MM * HR;
    ushort* q1b = p; p += (size_t)MM * HR;
    ushort* q2b = p; p += (size_t)MM * HR;
    ushort* k0b = p; p += (size_t)MM * HR;
    ushort* k1b = p; p += (size_t)MM * HR;
    ushort* k2b = p; p += (size_t)MM * HR;
    ushort* Hh  = p; p += (size_t)MM * DFF;
    ushort* Hl  = p; p += (size_t)MM * DFF;
    ushort* W1ph = p; p += 3 * 131072;
    ushort* W1pl = p; p += 3 * 131072;
    ushort* W2ph = p; p += 3 * 131072;
    ushort* W2pl = p; p += 3 * 131072;
    ushort* U0p = p; p += 3 * 32768;
    ushort* U1p = p; p += 3 * 32768;
    ushort* U2p = p; p += 3 * 32768;
    ushort* V0p = p; p += 3 * 32768;
    ushort* V1p = p; p += 3 * 32768;
    ushort* V2p = p; p += 3 * 32768;
    float* f = (float*)p;
    float* valA = f; f += (size_t)MM * DD;
    float* valB = f; f += (size_t)MM * DD;
    float* st0  = f; f += MM;
    float* st1  = f; f += MM;
    float* dst  = f; f += MM;
    float* Yb   = valA;   // in-place: ffn3 reads row then writes row

    packall_kernel<<<3840, 256, 0, stream>>>(W1, W2, U, V,
                                             W1ph, W1pl, W2ph, W2pl,
                                             U0p, U1p, U2p, V0p, V1p, V2p);

    embed_kernel<<<MM, 256, 0, stream>>>(ids, emb, pos, anchor_val, anchor_state,
                                         Ws, bs, valA, vA0, vA1, vA2, st0);
    float* s_in = st0;
    float* s_out = st1;
    for (int l = 0; l < 3; l++) {
        proj_kernel<<<dim3(129, 2), 256, 0, stream>>>(
            vA0, vA1, vA2,
            U0p + (size_t)l * 32768, U1p + (size_t)l * 32768, U2p + (size_t)l * 32768,
            V0p + (size_t)l * 32768, V1p + (size_t)l * 32768, V2p + (size_t)l * 32768,
            q0b, q1b, q2b, k0b, k1b, k2b);
        attn_kernel<<<BB * TB8, 256, 0, stream>>>(valA, s_in,
                                                  q0b, q1b, q2b, k0b, k1b, k2b,
                                                  valB, vB0, vB1, dst);
        state_kernel<<<BB, 1024, 0, stream>>>(s_in, dst, (l == 2) ? out : s_out);
        ffn1_kernel<<<dim3(129, 2), 256, 0, stream>>>(
            vB0, vB1,
            W1ph + (size_t)l * 131072, W1pl + (size_t)l * 131072, b1 + (size_t)l * DFF,
            Hh, Hl);
        ffn2_kernel<<<dim3(129, 2), 256, 0, stream>>>(
            Hh, Hl, valB,
            W2ph + (size_t)l * 131072, W2pl + (size_t)l * 131072, b2 + (size_t)l * DD,
            Yb);
        ffn3_kernel<<<(MM + 3) / 4, 256, 0, stream>>>(
            Yb, (l == 2) ? (out + MM) : valA, vA0, vA1, vA2);
        float* tmp = s_in; s_in = s_out; s_out = tmp;
    }
}

// Round 10
// 358.044 us; speedup vs baseline: 1.2930x; 1.0827x over previous
//
#include <hip/hip_runtime.h>
#include <hip/hip_bf16.h>
#include <math.h>

#define BB 2
#define SS 2048
#define NN 2049
#define MM (BB*NN)      // 4098 rows
#define DD 256
#define HR 128          // HEADS*RANK
#define NHEAD 4
#define WINW 64
#define DFF 512
#define EPSF 1e-6f
#define TB8 257         // ceil(NN/8) attn tiles per batch

typedef __attribute__((ext_vector_type(8))) short bf16x8;
typedef __attribute__((ext_vector_type(4))) float f32x4;

// ---------- helpers ----------
__device__ __forceinline__ float wave_sum(float v) {
    v += __shfl_down(v, 32, 64); v += __shfl_down(v, 16, 64);
    v += __shfl_down(v, 8, 64);  v += __shfl_down(v, 4, 64);
    v += __shfl_down(v, 2, 64);  v += __shfl_down(v, 1, 64);
    return v;
}
__device__ __forceinline__ float wave_max(float v) {
    v = fmaxf(v, __shfl_down(v, 32, 64)); v = fmaxf(v, __shfl_down(v, 16, 64));
    v = fmaxf(v, __shfl_down(v, 8, 64));  v = fmaxf(v, __shfl_down(v, 4, 64));
    v = fmaxf(v, __shfl_down(v, 2, 64));  v = fmaxf(v, __shfl_down(v, 1, 64));
    return v;
}
__device__ __forceinline__ float block_sum(float v, float* red) {
    v = wave_sum(v);
    __syncthreads();
    if ((threadIdx.x & 63) == 0) red[threadIdx.x >> 6] = v;
    __syncthreads();
    return red[0] + red[1] + red[2] + red[3];
}
__device__ __forceinline__ float sgnf(float x) {
    return (x > 0.f) ? 1.f : ((x < 0.f) ? -1.f : 0.f);
}
__device__ __forceinline__ ushort f2b(float x) {
    __hip_bfloat16 h = __float2bfloat16(x);
    return *(ushort*)&h;
}
__device__ __forceinline__ float b2f(ushort u) {
    unsigned int v = ((unsigned int)u) << 16;
    return *(float*)&v;
}
__device__ __forceinline__ void split3(float x, ushort& h, ushort& m, ushort& l) {
    h = f2b(x);
    float r1 = x - b2f(h);
    m = f2b(r1);
    l = f2b(r1 - b2f(m));
}
__device__ __forceinline__ void pack_map(int e, int N, int& k, int& n) {
    int j = e & 7;
    int l = (e >> 3) & 63;
    int c = e >> 9;
    int ntiles = N >> 4;
    int kt = c / ntiles, nt = c - kt * ntiles;
    k = kt * 32 + ((l >> 4) << 3) + j;
    n = nt * 16 + (l & 15);
}
// async global->LDS DMA, 16B per lane; lds dest = base + lane*16
__device__ __forceinline__ void dma16(const ushort* g, ushort* lds) {
    __builtin_amdgcn_global_load_lds(
        (const __attribute__((address_space(1))) unsigned int*)g,
        (__attribute__((address_space(3))) unsigned int*)lds,
        16, 0, 0);
}

// ---------- fused weight pack ----------
__global__ void packall_kernel(const float* __restrict__ W1, const float* __restrict__ W2,
                               const float* __restrict__ U,  const float* __restrict__ V,
                               ushort* __restrict__ W1ph, ushort* __restrict__ W1pl,
                               ushort* __restrict__ W2ph, ushort* __restrict__ W2pl,
                               ushort* __restrict__ U0, ushort* __restrict__ U1,
                               ushort* __restrict__ U2,
                               ushort* __restrict__ V0, ushort* __restrict__ V1,
                               ushort* __restrict__ V2) {
    int idx = blockIdx.x * 256 + threadIdx.x;
    int l = idx / 327680;
    int r = idx - l * 327680;
    if (l >= 3) return;
    int k, n;
    if (r < 131072) {
        int e = r;
        pack_map(e, 512, k, n);
        float s = W1[(size_t)l * 131072 + (size_t)k * 512 + n];
        ushort h = f2b(s);
        W1ph[(size_t)l * 131072 + e] = h;
        W1pl[(size_t)l * 131072 + e] = f2b(s - b2f(h));
    } else if (r < 262144) {
        int e = r - 131072;
        pack_map(e, 256, k, n);
        float s = W2[(size_t)l * 131072 + (size_t)k * 256 + n];
        ushort h = f2b(s);
        W2ph[(size_t)l * 131072 + e] = h;
        W2pl[(size_t)l * 131072 + e] = f2b(s - b2f(h));
    } else if (r < 294912) {
        int e = r - 262144;
        pack_map(e, 128, k, n);
        ushort h, m, lo;
        split3(U[(size_t)l * 32768 + (size_t)k * 128 + n], h, m, lo);
        U0[(size_t)l * 32768 + e] = h;
        U1[(size_t)l * 32768 + e] = m;
        U2[(size_t)l * 32768 + e] = lo;
    } else {
        int e = r - 294912;
        pack_map(e, 128, k, n);
        ushort h, m, lo;
        split3(V[(size_t)l * 32768 + (size_t)k * 128 + n], h, m, lo);
        V0[(size_t)l * 32768 + e] = h;
        V1[(size_t)l * 32768 + e] = m;
        V2[(size_t)l * 32768 + e] = lo;
    }
}

// ---------- embed ----------
__global__ void embed_kernel(const int* __restrict__ ids,
                             const float* __restrict__ emb,
                             const float* __restrict__ pos,
                             const float* __restrict__ anchor_val,
                             const float* __restrict__ anchor_state,
                             const float* __restrict__ Ws,
                             const float* __restrict__ bs,
                             float* __restrict__ val,
                             ushort* __restrict__ v0, ushort* __restrict__ v1,
                             ushort* __restrict__ v2,
                             float* __restrict__ state) {
    __shared__ float red[4];
    int row = blockIdx.x;
    int t = threadIdx.x;
    int b = row / NN, n = row % NN;
    float e;
    if (n == 0) {
        e = anchor_val[t];
    } else {
        int id = ids[b * SS + (n - 1)];
        e = emb[(size_t)id * DD + t] + pos[(size_t)(n - 1) * DD + t];
    }
    float ss = block_sum(e * e, red);
    float ts = block_sum(e * Ws[t], red);
    float rn = 1.f / fmaxf(sqrtf(ss), EPSF);
    float o = e * rn;
    size_t oi = (size_t)row * DD + t;
    val[oi] = o;
    ushort h, m, lo;
    split3(o, h, m, lo);
    v0[oi] = h; v1[oi] = m; v2[oi] = lo;
    if (t == 0) state[row] = (n == 0) ? anchor_state[0] : (ts + bs[0]);
}

// ---------- proj: 6-term MFMA, T=16, q|k per block, DMA-staged weights ----------
__global__ __launch_bounds__(256, 2)
void proj_kernel(const ushort* __restrict__ X0, const ushort* __restrict__ X1,
                 const ushort* __restrict__ X2,
                 const ushort* __restrict__ U0, const ushort* __restrict__ U1,
                 const ushort* __restrict__ U2,
                 const ushort* __restrict__ V0, const ushort* __restrict__ V1,
                 const ushort* __restrict__ V2,
                 ushort* __restrict__ q0, ushort* __restrict__ q1,
                 ushort* __restrict__ q2,
                 ushort* __restrict__ k0, ushort* __restrict__ k1,
                 ushort* __restrict__ k2) {
    __shared__ __align__(16) ushort stage[2][24 * 512];   // 48 KB
    int t = threadIdx.x;
    int w = t >> 6, l = t & 63;
    int lm = l & 15, quad = l >> 4;
    int m0 = blockIdx.x * 16;
    bool isQ = (blockIdx.y == 0);
    const ushort* P0 = isQ ? U0 : V0;
    const ushort* P1 = isQ ? U1 : V1;
    const ushort* P2 = isQ ? U2 : V2;
    const ushort* P[3] = {P0, P1, P2};
    int row0 = m0 + lm; if (row0 > MM - 1) row0 = MM - 1;

    #pragma unroll
    for (int i = 0; i < 6; i++) {
        int c = w * 6 + i;
        int p = c >> 3, ntl = c & 7;
        dma16(P[p] + ((size_t)(0 * 8 + ntl) * 64 + l) * 8,
              &stage[0][c * 512 + l * 8]);
    }
    __syncthreads();

    f32x4 acc[2];
    acc[0] = (f32x4)(0.f); acc[1] = (f32x4)(0.f);
    for (int kt = 0; kt < 8; kt++) {
        int cur = kt & 1;
        if (kt < 7) {
            #pragma unroll
            for (int i = 0; i < 6; i++) {
                int c = w * 6 + i;
                int p = c >> 3, ntl = c & 7;
                dma16(P[p] + ((size_t)((kt + 1) * 8 + ntl) * 64 + l) * 8,
                      &stage[cur ^ 1][c * 512 + l * 8]);
            }
        }
        int ko = kt * 32 + quad * 8;
        bf16x8 a0 = *(const bf16x8*)(X0 + (size_t)row0 * DD + ko);
        bf16x8 a1 = *(const bf16x8*)(X1 + (size_t)row0 * DD + ko);
        bf16x8 a2 = *(const bf16x8*)(X2 + (size_t)row0 * DD + ko);
        #pragma unroll
        for (int jj = 0; jj < 2; jj++) {
            int ntl = w * 2 + jj;
            bf16x8 b0 = *(const bf16x8*)&stage[cur][(0 * 8 + ntl) * 512 + l * 8];
            bf16x8 b1 = *(const bf16x8*)&stage[cur][(1 * 8 + ntl) * 512 + l * 8];
            bf16x8 b2 = *(const bf16x8*)&stage[cur][(2 * 8 + ntl) * 512 + l * 8];
            acc[jj] = __builtin_amdgcn_mfma_f32_16x16x32_bf16(a0, b0, acc[jj], 0, 0, 0);
            acc[jj] = __builtin_amdgcn_mfma_f32_16x16x32_bf16(a0, b1, acc[jj], 0, 0, 0);
            acc[jj] = __builtin_amdgcn_mfma_f32_16x16x32_bf16(a1, b0, acc[jj], 0, 0, 0);
            acc[jj] = __builtin_amdgcn_mfma_f32_16x16x32_bf16(a1, b1, acc[jj], 0, 0, 0);
            acc[jj] = __builtin_amdgcn_mfma_f32_16x16x32_bf16(a0, b2, acc[jj], 0, 0, 0);
            acc[jj] = __builtin_amdgcn_mfma_f32_16x16x32_bf16(a2, b0, acc[jj], 0, 0, 0);
        }
        __syncthreads();
    }
    ushort* o0 = isQ ? q0 : k0;
    ushort* o1 = isQ ? q1 : k1;
    ushort* o2 = isQ ? q2 : k2;
    #pragma unroll
    for (int jj = 0; jj < 2; jj++) {
        int n = (w * 2 + jj) * 16 + lm;
        #pragma unroll
        for (int r = 0; r < 4; r++) {
            int tok = m0 + quad * 4 + r;
            if (tok < MM) {
                ushort h, m, lo;
                split3(acc[jj][r], h, m, lo);
                size_t oi = (size_t)tok * HR + n;
                o0[oi] = h; o1[oi] = m; o2[oi] = lo;
            }
        }
    }
}

// ---------- attention (unchanged) ----------
__global__ __launch_bounds__(256, 2)
void attn_kernel(const float* __restrict__ val_in,
                 const float* __restrict__ state_in,
                 const ushort* __restrict__ q0, const ushort* __restrict__ q1,
                 const ushort* __restrict__ q2,
                 const ushort* __restrict__ k0, const ushort* __restrict__ k1,
                 const ushort* __restrict__ k2,
                 float* __restrict__ val_out,
                 ushort* __restrict__ vbH, ushort* __restrict__ vbM,
                 float* __restrict__ dstate_out) {
    __shared__ float sc4[NHEAD][8][148];
    __shared__ float wgt2[144][12];
    __shared__ float redS[8][4];
    __shared__ float redM[8][4];

    int b = blockIdx.x / TB8;
    int n0 = (blockIdx.x % TB8) * 8;
    int t = threadIdx.x;
    int w = t >> 6, l = t & 63;
    int lm = l & 15, quad = l >> 4;

    {
        int qrow = n0 + (lm & 7);
        if (qrow > NN - 1) qrow = NN - 1;
        size_t qa = ((size_t)(b * NN + qrow)) * HR + w * 32 + quad * 8;
        bf16x8 a0 = *(const bf16x8*)(q0 + qa);
        bf16x8 a1 = *(const bf16x8*)(q1 + qa);
        bf16x8 a2 = *(const bf16x8*)(q2 + qa);
        bf16x8 kf0[9], kf1[9], kf2[9];
        #pragma unroll
        for (int jt = 0; jt < 9; jt++) {
            int j = n0 - 64 + jt * 16 + lm;
            j = (j < 0) ? 0 : ((j > NN - 1) ? NN - 1 : j);
            size_t ka = ((size_t)(b * NN + j)) * HR + w * 32 + quad * 8;
            kf0[jt] = *(const bf16x8*)(k0 + ka);
            kf1[jt] = *(const bf16x8*)(k1 + ka);
            kf2[jt] = *(const bf16x8*)(k2 + ka);
        }
        #pragma unroll
        for (int jt = 0; jt < 9; jt++) {
            f32x4 acc = (f32x4)(0.f);
            acc = __builtin_amdgcn_mfma_f32_16x16x32_bf16(a0, kf0[jt], acc, 0, 0, 0);
            acc = __builtin_amdgcn_mfma_f32_16x16x32_bf16(a0, kf1[jt], acc, 0, 0, 0);
            acc = __builtin_amdgcn_mfma_f32_16x16x32_bf16(a1, kf0[jt], acc, 0, 0, 0);
            acc = __builtin_amdgcn_mfma_f32_16x16x32_bf16(a1, kf1[jt], acc, 0, 0, 0);
            acc = __builtin_amdgcn_mfma_f32_16x16x32_bf16(a0, kf2[jt], acc, 0, 0, 0);
            acc = __builtin_amdgcn_mfma_f32_16x16x32_bf16(a2, kf0[jt], acc, 0, 0, 0);
            if (quad < 2) {
                #pragma unroll
                for (int r = 0; r < 4; r++)
                    sc4[w][quad * 4 + r][jt * 16 + lm] = acc[r];
            }
        }
    }
    __syncthreads();

    {
        int m = t >> 5, p = t & 31;
        int n = n0 + m;
        bool tokv = (n < NN);
        float sv[5]; bool vv[5];
        float mx = -INFINITY;
        #pragma unroll
        for (int i = 0; i < 5; i++) {
            int tap = p + 32 * i;
            bool inb = (tap < 144);
            int tapc = inb ? tap : 0;
            int j = n0 - 64 + tapc;
            float s0 = sc4[0][m][tapc], s1 = sc4[1][m][tapc];
            float s2 = sc4[2][m][tapc], s3 = sc4[3][m][tapc];
            float s = fmaxf(fmaxf(s0, s1), fmaxf(s2, s3)) * 0.17677669529663687f;
            bool v = inb && tokv && (tap >= m) && (tap <= m + 128) && (j >= 0) && (j < NN);
            sv[i] = s; vv[i] = v;
            if (v) mx = fmaxf(mx, fabsf(s));
        }
        for (int off = 16; off > 0; off >>= 1) mx = fmaxf(mx, __shfl_xor(mx, off, 64));
        float ee[5];
        float sum = 0.f;
        #pragma unroll
        for (int i = 0; i < 5; i++) {
            ee[i] = vv[i] ? expf(fabsf(sv[i]) - mx) : 0.f;
            sum += ee[i];
        }
        for (int off = 16; off > 0; off >>= 1) sum += __shfl_xor(sum, off, 64);
        float inv = (sum > 0.f) ? 1.f / sum : 0.f;
        float ds = 0.f;
        #pragma unroll
        for (int i = 0; i < 5; i++) {
            int tap = p + 32 * i;
            if (tap < 144) {
                float wg = vv[i] ? sgnf(sv[i]) * ee[i] * inv : 0.f;
                wgt2[tap][m] = wg;
                if (vv[i]) ds += wg * state_in[b * NN + (n0 - 64 + tap)];
            }
        }
        for (int off = 16; off > 0; off >>= 1) ds += __shfl_xor(ds, off, 64);
        if (p == 0 && tokv) dstate_out[b * NN + n] = ds;
    }
    __syncthreads();

    {
        int d = (t >> 2) * 4;
        int tg = t & 3;
        int tok0 = tg * 2, tok1 = tg * 2 + 1;
        int jlo = (n0 >= 64) ? 0 : (64 - n0);
        int jhi = NN - 1 - n0 + 64; if (jhi > 135) jhi = 135;
        const float* vbase = val_in + ((size_t)(b * NN + n0 - 64)) * DD + d;
        f32x4 acc0 = (f32x4)(0.f), acc1 = (f32x4)(0.f);
        int jj = jlo;
        for (; jj + 3 <= jhi; jj += 4) {
            f32x4 v0 = *(const f32x4*)(vbase + (size_t)(jj + 0) * DD);
            f32x4 v1 = *(const f32x4*)(vbase + (size_t)(jj + 1) * DD);
            f32x4 v2 = *(const f32x4*)(vbase + (size_t)(jj + 2) * DD);
            f32x4 v3 = *(const f32x4*)(vbase + (size_t)(jj + 3) * DD);
            float wa0 = wgt2[jj + 0][tok0], wa1 = wgt2[jj + 0][tok1];
            float wb0 = wgt2[jj + 1][tok0], wb1 = wgt2[jj + 1][tok1];
            float wc0 = wgt2[jj + 2][tok0], wc1 = wgt2[jj + 2][tok1];
            float wd0 = wgt2[jj + 3][tok0], wd1 = wgt2[jj + 3][tok1];
            #pragma unroll
            for (int c = 0; c < 4; c++) {
                acc0[c] += v0[c] * wa0 + v1[c] * wb0 + v2[c] * wc0 + v3[c] * wd0;
                acc1[c] += v0[c] * wa1 + v1[c] * wb1 + v2[c] * wc1 + v3[c] * wd1;
            }
        }
        for (; jj <= jhi; jj++) {
            f32x4 v = *(const f32x4*)(vbase + (size_t)jj * DD);
            float w0 = wgt2[jj][tok0], w1 = wgt2[jj][tok1];
            #pragma unroll
            for (int c = 0; c < 4; c++) {
                acc0[c] += v[c] * w0;
                acc1[c] += v[c] * w1;
            }
        }
        f32x4 u[2]; f32x4 ac[2]; ac[0] = acc0; ac[1] = acc1;
        #pragma unroll
        for (int ti = 0; ti < 2; ti++) {
            int tok = tg * 2 + ti;
            int n = n0 + tok;
            f32x4 vold = (f32x4)(0.f);
            if (n < NN) vold = *(const f32x4*)(val_in + ((size_t)(b * NN + n)) * DD + d);
            u[ti] = vold + ac[ti];
            float s = u[ti][0]*u[ti][0] + u[ti][1]*u[ti][1] + u[ti][2]*u[ti][2] + u[ti][3]*u[ti][3];
            float mb = fmaxf(fmaxf(fabsf(ac[ti][0]), fabsf(ac[ti][1])),
                             fmaxf(fabsf(ac[ti][2]), fabsf(ac[ti][3])));
            for (int off = 4; off <= 32; off <<= 1) {
                s += __shfl_xor(s, off, 64);
                mb = fmaxf(mb, __shfl_xor(mb, off, 64));
            }
            if ((l >> 2) == 0) { redS[tok][w] = s; redM[tok][w] = mb; }
        }
        __syncthreads();
        #pragma unroll
        for (int ti = 0; ti < 2; ti++) {
            int tok = tg * 2 + ti;
            int n = n0 + tok;
            if (n < NN) {
                float ss = redS[tok][0] + redS[tok][1] + redS[tok][2] + redS[tok][3];
                float mab = fmaxf(fmaxf(redM[tok][0], redM[tok][1]),
                                  fmaxf(redM[tok][2], redM[tok][3]));
                float rn = 1.f / fmaxf(sqrtf(ss), EPSF);
                f32x4 o = u[ti];
                if (mab > 0.f) { o[0] *= rn; o[1] *= rn; o[2] *= rn; o[3] *= rn; }
                size_t oi = ((size_t)(b * NN + n)) * DD + d;
                *(f32x4*)(val_out + oi) = o;
                ushort4 hv, mv;
                {
                    ushort h0 = f2b(o[0]); hv.x = h0; mv.x = f2b(o[0] - b2f(h0));
                    ushort h1 = f2b(o[1]); hv.y = h1; mv.y = f2b(o[1] - b2f(h1));
                    ushort h2 = f2b(o[2]); hv.z = h2; mv.z = f2b(o[2] - b2f(h2));
                    ushort h3 = f2b(o[3]); hv.w = h3; mv.w = f2b(o[3] - b2f(h3));
                }
                *(ushort4*)(vbH + oi) = hv;
                *(ushort4*)(vbM + oi) = mv;
            }
        }
    }
}

// ---------- ffn1: GEMM1 + gelu -> H hi/lo, T=16, N-half; fused state update ----------
__global__ __launch_bounds__(256, 2)
void ffn1_kernel(const ushort* __restrict__ XbH, const ushort* __restrict__ XbM,
                 const ushort* __restrict__ W1h, const ushort* __restrict__ W1l,
                 const float*  __restrict__ b1,
                 ushort* __restrict__ Hh, ushort* __restrict__ Hl,
                 const float* __restrict__ state_in, const float* __restrict__ dstate,
                 float* __restrict__ state_out) {
    __shared__ __align__(16) ushort stage[2][32 * 512];   // 64 KB
    int t = threadIdx.x;

    if (blockIdx.x == 257) {   // fused state signed-softmax, batch = blockIdx.y
        float* red = (float*)&stage[0][0];
        int b = blockIdx.y;
        float lmax = -INFINITY;
        for (int n = t; n < NN; n += 256) {
            float x = state_in[b * NN + n] + dstate[b * NN + n];
            lmax = fmaxf(lmax, fabsf(x));
        }
        lmax = wave_max(lmax);
        if ((t & 63) == 0) red[t >> 6] = lmax;
        __syncthreads();
        float m = fmaxf(fmaxf(red[0], red[1]), fmaxf(red[2], red[3]));
        float lsum = 0.f;
        for (int n = t; n < NN; n += 256)
            lsum += expf(fabsf(state_in[b * NN + n] + dstate[b * NN + n]) - m);
        lsum = wave_sum(lsum);
        __syncthreads();
        if ((t & 63) == 0) red[4 + (t >> 6)] = lsum;
        __syncthreads();
        float inv = 1.f / (red[4] + red[5] + red[6] + red[7]);
        for (int n = t; n < NN; n += 256) {
            float x = state_in[b * NN + n] + dstate[b * NN + n];
            state_out[b * NN + n] = sgnf(x) * expf(fabsf(x) - m) * inv;
        }
        return;
    }

    int w = t >> 6, l = t & 63;
    int lm = l & 15, quad = l >> 4;
    int m0 = blockIdx.x * 16;
    int nh = blockIdx.y;
    int row0 = m0 + lm; if (row0 > MM - 1) row0 = MM - 1;

    #pragma unroll
    for (int i = 0; i < 8; i++) {
        int c = w * 8 + i;
        int p = c >> 4, ntl = c & 15;
        const ushort* src = (p ? W1l : W1h) + ((size_t)(0 * 32 + nh * 16 + ntl) * 64 + l) * 8;
        dma16(src, &stage[0][c * 512 + l * 8]);
    }
    __syncthreads();

    f32x4 acc[4];
    #pragma unroll
    for (int jj = 0; jj < 4; jj++) acc[jj] = (f32x4)(0.f);

    for (int kt = 0; kt < 8; kt++) {
        int cur = kt & 1;
        if (kt < 7) {
            #pragma unroll
            for (int i = 0; i < 8; i++) {
                int c = w * 8 + i;
                int p = c >> 4, ntl = c & 15;
                const ushort* src = (p ? W1l : W1h) +
                    ((size_t)((kt + 1) * 32 + nh * 16 + ntl) * 64 + l) * 8;
                dma16(src, &stage[cur ^ 1][c * 512 + l * 8]);
            }
        }
        int ko = kt * 32 + quad * 8;
        bf16x8 ah = *(const bf16x8*)(XbH + (size_t)row0 * DD + ko);
        bf16x8 am = *(const bf16x8*)(XbM + (size_t)row0 * DD + ko);
        #pragma unroll
        for (int jj = 0; jj < 4; jj++) {
            int ntl = w * 4 + jj;
            bf16x8 bh = *(const bf16x8*)&stage[cur][ntl * 512 + l * 8];
            bf16x8 bl = *(const bf16x8*)&stage[cur][(16 + ntl) * 512 + l * 8];
            acc[jj] = __builtin_amdgcn_mfma_f32_16x16x32_bf16(ah, bh, acc[jj], 0, 0, 0);
            acc[jj] = __builtin_amdgcn_mfma_f32_16x16x32_bf16(am, bh, acc[jj], 0, 0, 0);
            acc[jj] = __builtin_amdgcn_mfma_f32_16x16x32_bf16(ah, bl, acc[jj], 0, 0, 0);
        }
        __syncthreads();
    }
    #pragma unroll
    for (int jj = 0; jj < 4; jj++) {
        int gn = nh * 256 + (w * 4 + jj) * 16 + lm;
        float bb = b1[gn];
        #pragma unroll
        for (int r = 0; r < 4; r++) {
            int tok = m0 + quad * 4 + r;
            if (tok < MM) {
                float x = acc[jj][r] + bb;
                float g = 0.5f * x * (1.f + erff(x * 0.70710678118654752f));
                ushort gh = f2b(g);
                size_t oi = (size_t)tok * DFF + gn;
                Hh[oi] = gh;
                Hl[oi] = f2b(g - b2f(gh));
            }
        }
    }
}

// ---------- ffn2: GEMM2 + residual + bias -> Y (f32), T=16, N-half ----------
__global__ __launch_bounds__(256, 2)
void ffn2_kernel(const ushort* __restrict__ Hh, const ushort* __restrict__ Hl,
                 const float*  __restrict__ Xf,
                 const ushort* __restrict__ W2h, const ushort* __restrict__ W2l,
                 const float*  __restrict__ b2,
                 float* __restrict__ Yb) {
    __shared__ __align__(16) ushort stage[2][16 * 512];   // 32 KB
    int t = threadIdx.x;
    int w = t >> 6, l = t & 63;
    int lm = l & 15, quad = l >> 4;
    int m0 = blockIdx.x * 16;
    int nh = blockIdx.y;
    int row0 = m0 + lm; if (row0 > MM - 1) row0 = MM - 1;

    #pragma unroll
    for (int i = 0; i < 4; i++) {
        int c = w * 4 + i;
        int p = c >> 3, ntl = c & 7;
        const ushort* src = (p ? W2l : W2h) + ((size_t)(0 * 16 + nh * 8 + ntl) * 64 + l) * 8;
        dma16(src, &stage[0][c * 512 + l * 8]);
    }
    __syncthreads();

    f32x4 acc[2];
    acc[0] = (f32x4)(0.f); acc[1] = (f32x4)(0.f);

    for (int kt = 0; kt < 16; kt++) {
        int cur = kt & 1;
        if (kt < 15) {
            #pragma unroll
            for (int i = 0; i < 4; i++) {
                int c = w * 4 + i;
                int p = c >> 3, ntl = c & 7;
                const ushort* src = (p ? W2l : W2h) +
                    ((size_t)((kt + 1) * 16 + nh * 8 + ntl) * 64 + l) * 8;
                dma16(src, &stage[cur ^ 1][c * 512 + l * 8]);
            }
        }
        int ko = kt * 32 + quad * 8;
        bf16x8 ah = *(const bf16x8*)(Hh + (size_t)row0 * DFF + ko);
        bf16x8 al = *(const bf16x8*)(Hl + (size_t)row0 * DFF + ko);
        #pragma unroll
        for (int jj = 0; jj < 2; jj++) {
            int ntl = w * 2 + jj;
            bf16x8 bh = *(const bf16x8*)&stage[cur][ntl * 512 + l * 8];
            bf16x8 bl = *(const bf16x8*)&stage[cur][(8 + ntl) * 512 + l * 8];
            acc[jj] = __builtin_amdgcn_mfma_f32_16x16x32_bf16(ah, bh, acc[jj], 0, 0, 0);
            acc[jj] = __builtin_amdgcn_mfma_f32_16x16x32_bf16(al, bh, acc[jj], 0, 0, 0);
            acc[jj] = __builtin_amdgcn_mfma_f32_16x16x32_bf16(ah, bl, acc[jj], 0, 0, 0);
        }
        __syncthreads();
    }
    #pragma unroll
    for (int jj = 0; jj < 2; jj++) {
        int gn = nh * 128 + (w * 2 + jj) * 16 + lm;
        float bb = b2[gn];
        #pragma unroll
        for (int r = 0; r < 4; r++) {
            int tok = m0 + quad * 4 + r;
            if (tok < MM) {
                size_t oi = (size_t)tok * DD + gn;
                Yb[oi] = Xf[oi] + acc[jj][r] + bb;
            }
        }
    }
}

// ---------- ffn3: row norm + split3 ----------
__global__ void ffn3_kernel(const float* __restrict__ Yb,
                            float* __restrict__ val_out,
                            ushort* __restrict__ o0, ushort* __restrict__ o1,
                            ushort* __restrict__ o2) {
    int t = threadIdx.x;
    int w = t >> 6, l = t & 63;
    int row = blockIdx.x * 4 + w;
    if (row >= MM) return;
    f32x4 y = *(const f32x4*)(Yb + (size_t)row * DD + l * 4);
    float s = y[0]*y[0] + y[1]*y[1] + y[2]*y[2] + y[3]*y[3];
    #pragma unroll
    for (int off = 1; off < 64; off <<= 1) s += __shfl_xor(s, off, 64);
    float rn = 1.f / fmaxf(sqrtf(s), EPSF);
    f32x4 o;
    o[0] = y[0] * rn; o[1] = y[1] * rn; o[2] = y[2] * rn; o[3] = y[3] * rn;
    size_t oi = (size_t)row * DD + l * 4;
    *(f32x4*)(val_out + oi) = o;
    ushort4 h4, m4, l4;
    ushort hh, mm, ll;
    split3(o[0], hh, mm, ll); h4.x = hh; m4.x = mm; l4.x = ll;
    split3(o[1], hh, mm, ll); h4.y = hh; m4.y = mm; l4.y = ll;
    split3(o[2], hh, mm, ll); h4.z = hh; m4.z = mm; l4.z = ll;
    split3(o[3], hh, mm, ll); h4.w = hh; m4.w = mm; l4.w = ll;
    *(ushort4*)(o0 + oi) = h4;
    *(ushort4*)(o1 + oi) = m4;
    *(ushort4*)(o2 + oi) = l4;
}

extern "C" void kernel_launch(void* const* d_in, const int* in_sizes, int n_in,
                              void* d_out, int out_size, void* d_ws, size_t ws_size,
                              hipStream_t stream) {
    const int*   ids          = (const int*)d_in[0];
    const float* emb          = (const float*)d_in[1];
    const float* pos          = (const float*)d_in[2];
    const float* anchor_val   = (const float*)d_in[3];
    const float* anchor_state = (const float*)d_in[4];
    const float* Ws           = (const float*)d_in[5];
    const float* bs           = (const float*)d_in[6];
    const float* U            = (const float*)d_in[7];
    const float* V            = (const float*)d_in[8];
    const float* W1           = (const float*)d_in[9];
    const float* b1           = (const float*)d_in[10];
    const float* W2           = (const float*)d_in[11];
    const float* b2           = (const float*)d_in[12];
    float* out = (float*)d_out;

    ushort* p = (ushort*)d_ws;
    ushort* vA0 = p; p += (size_t)MM * DD;
    ushort* vA1 = p; p += (size_t)MM * DD;
    ushort* vA2 = p; p += (size_t)MM * DD;
    ushort* vB0 = p; p += (size_t)MM * DD;
    ushort* vB1 = p; p += (size_t)MM * DD;
    ushort* q0b = p; p += (size_t)MM * HR;
    ushort* q1b = p; p += (size_t)MM * HR;
    ushort* q2b = p; p += (size_t)MM * HR;
    ushort* k0b = p; p += (size_t)MM * HR;
    ushort* k1b = p; p += (size_t)MM * HR;
    ushort* k2b = p; p += (size_t)MM * HR;
    ushort* Hh  = p; p += (size_t)MM * DFF;
    ushort* Hl  = p; p += (size_t)MM * DFF;
    ushort* W1ph = p; p += 3 * 131072;
    ushort* W1pl = p; p += 3 * 131072;
    ushort* W2ph = p; p += 3 * 131072;
    ushort* W2pl = p; p += 3 * 131072;
    ushort* U0p = p; p += 3 * 32768;
    ushort* U1p = p; p += 3 * 32768;
    ushort* U2p = p; p += 3 * 32768;
    ushort* V0p = p; p += 3 * 32768;
    ushort* V1p = p; p += 3 * 32768;
    ushort* V2p = p; p += 3 * 32768;
    float* f = (float*)p;
    float* valA = f; f += (size_t)MM * DD;
    float* valB = f; f += (size_t)MM * DD;
    float* st0  = f; f += MM;
    float* st1  = f; f += MM;
    float* dst  = f; f += MM;
    float* Yb   = valA;   // in-place: ffn3 reads row then writes row

    packall_kernel<<<3840, 256, 0, stream>>>(W1, W2, U, V,
                                             W1ph, W1pl, W2ph, W2pl,
                                             U0p, U1p, U2p, V0p, V1p, V2p);

    embed_kernel<<<MM, 256, 0, stream>>>(ids, emb, pos, anchor_val, anchor_state,
                                         Ws, bs, valA, vA0, vA1, vA2, st0);
    float* s_in = st0;
    float* s_out = st1;
    for (int l = 0; l < 3; l++) {
        proj_kernel<<<dim3(257, 2), 256, 0, stream>>>(
            vA0, vA1, vA2,
            U0p + (size_t)l * 32768, U1p + (size_t)l * 32768, U2p + (size_t)l * 32768,
            V0p + (size_t)l * 32768, V1p + (size_t)l * 32768, V2p + (size_t)l * 32768,
            q0b, q1b, q2b, k0b, k1b, k2b);
        attn_kernel<<<BB * TB8, 256, 0, stream>>>(valA, s_in,
                                                  q0b, q1b, q2b, k0b, k1b, k2b,
                                                  valB, vB0, vB1, dst);
        ffn1_kernel<<<dim3(258, 2), 256, 0, stream>>>(
            vB0, vB1,
            W1ph + (size_t)l * 131072, W1pl + (size_t)l * 131072, b1 + (size_t)l * DFF,
            Hh, Hl,
            s_in, dst, (l == 2) ? out : s_out);
        ffn2_kernel<<<dim3(257, 2), 256, 0, stream>>>(
            Hh, Hl, valB,
            W2ph + (size_t)l * 131072, W2pl + (size_t)l * 131072, b2 + (size_t)l * DD,
            Yb);
        ffn3_kernel<<<(MM + 3) / 4, 256, 0, stream>>>(
            Yb, (l == 2) ? (out + MM) : valA, vA0, vA1, vA2);
        float* tmp = s_in; s_in = s_out; s_out = tmp;
    }
}